// Round 13
// baseline (605.147 us; speedup 1.0000x reference)
//
#include <hip/hip_runtime.h>
#include <hip/hip_bf16.h>
#include <stdint.h>
#include <stddef.h>

using bf16  = __hip_bfloat16;
using bf162 = __hip_bfloat162;

typedef __bf16 bvec8 __attribute__((ext_vector_type(8)));
typedef float  fvec4 __attribute__((ext_vector_type(4)));

// ---------- helpers ----------
struct __align__(16) bf16x8 { bf162 a, b, c, d; };

__device__ __forceinline__ void bf8_to_f(const bf16* p, float* o) {
    bf16x8 v = *reinterpret_cast<const bf16x8*>(p);
    o[0] = __bfloat162float(v.a.x); o[1] = __bfloat162float(v.a.y);
    o[2] = __bfloat162float(v.b.x); o[3] = __bfloat162float(v.b.y);
    o[4] = __bfloat162float(v.c.x); o[5] = __bfloat162float(v.c.y);
    o[6] = __bfloat162float(v.d.x); o[7] = __bfloat162float(v.d.y);
}

__device__ __forceinline__ float wred_sum(float v) {
    #pragma unroll
    for (int o = 32; o > 0; o >>= 1) v += __shfl_xor(v, o);
    return v;
}

__device__ __forceinline__ float wred_max(float v) {
    #pragma unroll
    for (int o = 32; o > 0; o >>= 1) v = fmaxf(v, __shfl_xor(v, o));
    return v;
}

__device__ __forceinline__ float lrelu(float x) { return (x > 0.f) ? x : 0.2f * x; }

__device__ __forceinline__ fvec4 mfma16(bvec8 a, bvec8 b, fvec4 c) {
    return __builtin_amdgcn_mfma_f32_16x16x32_bf16(a, b, c, 0, 0, 0);
}

__device__ __forceinline__ bvec8 ldA(const bf16* p) {
    return *reinterpret_cast<const bvec8*>(p);
}
__device__ __forceinline__ bvec8 ldA(const float* p) {
    float4 f0 = *reinterpret_cast<const float4*>(p);
    float4 f1 = *reinterpret_cast<const float4*>(p + 4);
    union { bvec8 v; bf16 h[8]; } u;
    u.h[0] = __float2bfloat16(f0.x); u.h[1] = __float2bfloat16(f0.y);
    u.h[2] = __float2bfloat16(f0.z); u.h[3] = __float2bfloat16(f0.w);
    u.h[4] = __float2bfloat16(f1.x); u.h[5] = __float2bfloat16(f1.y);
    u.h[6] = __float2bfloat16(f1.z); u.h[7] = __float2bfloat16(f1.w);
    return u.v;
}

// ---------- edge dtype detection ----------
__global__ void detect_kernel(const int* __restrict__ ei, int E, int* __restrict__ flags) {
    __shared__ int zc;
    if (threadIdx.x == 0) zc = 0;
    __syncthreads();
    int nodd = E / 2; if (nodd > 1024) nodd = 1024;
    for (int i = threadIdx.x; i < nodd; i += blockDim.x)
        if (ei[2 * i + 1] == 0) atomicAdd(&zc, 1);
    __syncthreads();
    if (threadIdx.x == 0) flags[0] = (zc > nodd / 2) ? 1 : 0;
}

__global__ void conv_edges_kernel(const int* __restrict__ ei, int* __restrict__ src32,
                                  int* __restrict__ dst32, int E, int N,
                                  const int* __restrict__ flags) {
    const int e = blockIdx.x * blockDim.x + threadIdx.x;
    if (e >= E) return;
    int s, d;
    if (flags[0]) { s = ei[2 * e]; d = ei[2 * (E + e)]; }
    else          { s = ei[e];     d = ei[E + e]; }
    src32[e] = (s < 0) ? 0 : ((s >= N) ? N - 1 : s);
    dst32[e] = (d < 0) ? 0 : ((d >= N) ? N - 1 : d);
}

// ---------- CSR build ----------
__global__ void zero2_kernel(int* __restrict__ p1, int* __restrict__ p2, int n) {
    int i = blockIdx.x * blockDim.x + threadIdx.x;
    if (i < n) { p1[i] = 0; p2[i] = 0; }
}

__global__ void hist_kernel(const int* __restrict__ dst32, int* __restrict__ cnt, int E) {
    int e = blockIdx.x * blockDim.x + threadIdx.x;
    if (e < E) atomicAdd(&cnt[dst32[e]], 1);
}

// 16-wave shfl-based exclusive scan: cnt[0..N) -> row_ptr[0..N]
__global__ __launch_bounds__(1024) void scan_kernel(const int* __restrict__ cnt,
                                                    int* __restrict__ row_ptr, int N) {
    __shared__ int wsum[16];
    __shared__ int carry;
    const int tid = threadIdx.x, lane = tid & 63, wid = tid >> 6;
    if (tid == 0) { carry = 0; row_ptr[0] = 0; }
    __syncthreads();
    for (int base = 0; base < N; base += 1024) {
        int i = base + tid;
        int v = (i < N) ? cnt[i] : 0;
        int s = v;
        #pragma unroll
        for (int o = 1; o < 64; o <<= 1) {
            int t = __shfl_up(s, o);
            if (lane >= o) s += t;
        }
        if (lane == 63) wsum[wid] = s;
        __syncthreads();
        if (wid == 0 && lane < 16) {
            int ws = wsum[lane];
            #pragma unroll
            for (int o = 1; o < 16; o <<= 1) {
                int t = __shfl_up(ws, o);
                if (lane >= o) ws += t;
            }
            wsum[lane] = ws;
        }
        __syncthreads();
        int add = carry + (wid > 0 ? wsum[wid - 1] : 0);
        if (i < N) row_ptr[i + 1] = s + add;
        __syncthreads();
        if (tid == 0) carry += wsum[15];
        __syncthreads();
    }
}

__global__ void fill_csr_kernel(const int* __restrict__ src32, const int* __restrict__ dst32,
                                const int* __restrict__ row_ptr, int* __restrict__ cursor,
                                int* __restrict__ col_src, int E) {
    int e = blockIdx.x * blockDim.x + threadIdx.x;
    if (e >= E) return;
    int d = dst32[e];
    int pos = atomicAdd(&cursor[d], 1);
    col_src[row_ptr[d] + pos] = src32[e];
}

// ---------- all weight converts, LDS-tiled transpose (coalesced both sides) ----------
struct TEnt { const float* src; bf16* dst; int K, N, Kp, Np, tstart; };
struct TTab { TEnt e[12]; int n; };

__global__ __launch_bounds__(256) void wconv_t_kernel(TTab tab) {
    __shared__ float tile[32][33];
    const int b = blockIdx.x;
    int wi = 0;
    #pragma unroll 1
    for (int i = 1; i < tab.n; ++i) if (b >= tab.e[i].tstart) wi = i;
    const TEnt w = tab.e[wi];
    const int tidx = b - w.tstart;
    const int ntk = w.Kp >> 5;
    const int tn = tidx / ntk, tk = tidx - tn * ntk;
    const int k0 = tk * 32, n0 = tn * 32;
    const int tx = threadIdx.x & 31, ty = threadIdx.x >> 5;   // 32 x 8
    #pragma unroll
    for (int j = 0; j < 4; ++j) {
        int k = k0 + ty * 4 + j;
        int n = n0 + tx;
        tile[ty * 4 + j][tx] = (k < w.K && n < w.N) ? w.src[(size_t)k * w.N + n] : 0.f;
    }
    __syncthreads();
    #pragma unroll
    for (int j = 0; j < 4; ++j) {
        int n = n0 + ty * 4 + j;
        int k = k0 + tx;
        w.dst[(size_t)n * w.Kp + k] = __float2bfloat16(tile[tx][ty * 4 + j]);
    }
}

// ---------- x -> bf16, row stride 2128, fully vectorized ----------
__global__ __launch_bounds__(256) void conv_x_kernel(const float* __restrict__ x,
                                                     bf16* __restrict__ xbf) {
    const int r = blockIdx.x;
    const float* xr = x + (size_t)r * 2100;
    bf16* orow = xbf + (size_t)r * 2128;
    #pragma unroll
    for (int pass = 0; pass < 2; ++pass) {
        int c0 = pass * 2048 + threadIdx.x * 8;
        if (c0 >= 2128) continue;
        union { uint4 u; bf16 h[8]; } ob;
        if (c0 + 8 <= 2100) {
            float4 f0 = *reinterpret_cast<const float4*>(xr + c0);
            float4 f1 = *reinterpret_cast<const float4*>(xr + c0 + 4);
            ob.h[0] = __float2bfloat16(f0.x); ob.h[1] = __float2bfloat16(f0.y);
            ob.h[2] = __float2bfloat16(f0.z); ob.h[3] = __float2bfloat16(f0.w);
            ob.h[4] = __float2bfloat16(f1.x); ob.h[5] = __float2bfloat16(f1.y);
            ob.h[6] = __float2bfloat16(f1.z); ob.h[7] = __float2bfloat16(f1.w);
        } else {
            #pragma unroll
            for (int j = 0; j < 8; ++j) {
                int c = c0 + j;
                ob.h[j] = __float2bfloat16((c < 2100) ? xr[c] : 0.f);
            }
        }
        *reinterpret_cast<uint4*>(orow + c0) = ob.u;
    }
}

// ---------- fused bias prep ----------
__global__ void bias_fuse_kernel(const float* l1_b, const float* c1_b, float* bsum1,
                                 const float* l2_b, const float* c2_b, float* bsum2,
                                 const float* dr_b, const float* dp_b, float* ddb) {
    int i = blockIdx.x * blockDim.x + threadIdx.x;
    if (i < 512)       bsum1[i] = l1_b[i] + c1_b[i];
    else if (i < 1024) bsum2[i - 512] = l2_b[i - 512] + c2_b[i - 512];
    else if (i < 1152) ddb[i - 1024] = dr_b[i - 1024];
    else if (i < 1280) ddb[i - 1024] = dp_b[i - 1152];
}

// ---------- block-1 logits from xin_bf: one wave per node, K=256 ----------
__global__ __launch_bounds__(64) void logits_bf16_kernel(
    const bf16* __restrict__ X,
    const float* __restrict__ Vs, const float* __restrict__ Vd,
    float* __restrict__ a_s, float* __restrict__ a_d)
{
    const int n = blockIdx.x, lane = threadIdx.x;
    const int c0 = lane * 4;
    union { uint2 u; bf16 h[4]; } ub;
    ub.u = *reinterpret_cast<const uint2*>(X + (size_t)n * 256 + c0);
    const float vv[4] = {__bfloat162float(ub.h[0]), __bfloat162float(ub.h[1]),
                         __bfloat162float(ub.h[2]), __bfloat162float(ub.h[3])};
    float ss0=0,ss1=0,ss2=0,ss3=0, dd0=0,dd1=0,dd2=0,dd3=0;
    #pragma unroll
    for (int j = 0; j < 4; ++j) {
        float4 vs = *reinterpret_cast<const float4*>(Vs + (size_t)(c0 + j) * 4);
        float4 vd = *reinterpret_cast<const float4*>(Vd + (size_t)(c0 + j) * 4);
        ss0 = fmaf(vv[j], vs.x, ss0); ss1 = fmaf(vv[j], vs.y, ss1);
        ss2 = fmaf(vv[j], vs.z, ss2); ss3 = fmaf(vv[j], vs.w, ss3);
        dd0 = fmaf(vv[j], vd.x, dd0); dd1 = fmaf(vv[j], vd.y, dd1);
        dd2 = fmaf(vv[j], vd.z, dd2); dd3 = fmaf(vv[j], vd.w, dd3);
    }
    ss0 = wred_sum(ss0); ss1 = wred_sum(ss1); ss2 = wred_sum(ss2); ss3 = wred_sum(ss3);
    dd0 = wred_sum(dd0); dd1 = wred_sum(dd1); dd2 = wred_sum(dd2); dd3 = wred_sum(dd3);
    if (lane == 0) {
        a_s[n*4+0]=ss0; a_s[n*4+1]=ss1; a_s[n*4+2]=ss2; a_s[n*4+3]=ss3;
        a_d[n*4+0]=dd0; a_d[n*4+1]=dd1; a_d[n*4+2]=dd2; a_d[n*4+3]=dd3;
    }
}

// ---------- MFMA GEMM: C[M,Nn] = A[M,K] @ Bt[Nn,K]^T (+bias, relu) ----------
template <int FM, bool RELU, typename AT>
__global__ __launch_bounds__(256) void mfma_gemm_kernel(
    const AT* __restrict__ A, int lda,
    const bf16* __restrict__ Bt, int ldb,
    const float* __restrict__ bias,
    float* __restrict__ Cf, int ldcf,
    bf16* __restrict__ Cb, int ldcb,
    int M, int Nn, int K)
{
    const int tid  = threadIdx.x;
    const int w    = tid >> 6, lane = tid & 63;
    const int wr   = w >> 1,   wc   = w & 1;
    const int m0   = blockIdx.y * (FM * 32) + wr * (FM * 16);
    const int n0   = blockIdx.x * 64 + wc * 32;
    const int lrow = lane & 15;
    const int lk8  = (lane >> 4) * 8;

    const AT* Ap[FM];
    #pragma unroll
    for (int i = 0; i < FM; ++i) {
        int r = m0 + i * 16 + lrow;
        if (r > M - 1) r = M - 1;
        Ap[i] = A + (size_t)r * lda + lk8;
    }
    const bf16* Bp = Bt + (size_t)(n0 + lrow) * ldb + lk8;
    const size_t b16 = (size_t)16 * ldb;

    fvec4 acc[FM][2];
    const fvec4 z = {0.f, 0.f, 0.f, 0.f};
    #pragma unroll
    for (int i = 0; i < FM; ++i) { acc[i][0] = z; acc[i][1] = z; }

    #pragma unroll 2
    for (int k = 0; k < K; k += 32) {
        bvec8 b0 = *reinterpret_cast<const bvec8*>(Bp + k);
        bvec8 b1 = *reinterpret_cast<const bvec8*>(Bp + k + b16);
        #pragma unroll
        for (int i = 0; i < FM; ++i) {
            bvec8 a = ldA(Ap[i] + k);
            acc[i][0] = mfma16(a, b0, acc[i][0]);
            acc[i][1] = mfma16(a, b1, acc[i][1]);
        }
    }

    const int r4 = (lane >> 4) * 4;
    #pragma unroll
    for (int fn = 0; fn < 2; ++fn) {
        const int col = n0 + fn * 16 + lrow;
        if (col >= Nn) continue;
        const float bz = bias ? bias[col] : 0.f;
        #pragma unroll
        for (int fm = 0; fm < FM; ++fm) {
            const int rbase = m0 + fm * 16 + r4;
            #pragma unroll
            for (int r = 0; r < 4; ++r) {
                const int row = rbase + r;
                if (row >= M) continue;
                float v = acc[fm][fn][r] + bz;
                if (RELU) v = fmaxf(v, 0.f);
                if (Cf) Cf[(size_t)row * ldcf + col] = v;
                if (Cb) Cb[(size_t)row * ldcb + col] = __float2bfloat16(v);
            }
        }
    }
}

// ---------- dual-output MFMA GEMM, 128x256 block, 8 waves, wave tile 64x64 ----------
// 1D grid with bijective chunked XCD swizzle (m204): all 4 col-blocks of a
// row-strip land in one XCD's chunk -> A panel cached in that XCD's L2.
// cols 0..511 -> xs (bf16), 512..1023 -> hB (f32)+bias.
__global__ __launch_bounds__(512) void mfma_gemm_dual_kernel(
    const bf16* __restrict__ A, int lda,
    const bf16* __restrict__ Bt, int ldb,
    const float* __restrict__ biasU,
    bf16* __restrict__ xs, float* __restrict__ hB,
    int M, int K, int nwg)
{
    // hardware bid -> logical tile id, chunked per XCD
    const int bid = blockIdx.x;
    const int q = nwg >> 3, r = nwg & 7;
    const int xcd = bid & 7, idx = bid >> 3;
    const int sbid = (xcd < r ? xcd * (q + 1) : r * (q + 1) + (xcd - r) * q) + idx;
    const int by = sbid >> 2, bx = sbid & 3;

    const int tid  = threadIdx.x;
    const int w    = tid >> 6, lane = tid & 63;
    const int wr   = w >> 2,   wc   = w & 3;       // 2 x 4 waves
    const int m0   = by * 128 + wr * 64;
    const int n0   = bx * 256 + wc * 64;
    const int lrow = lane & 15;
    const int lk8  = (lane >> 4) * 8;

    const bf16* Ap[4];
    const bf16* Bp[4];
    #pragma unroll
    for (int i = 0; i < 4; ++i) {
        int rr = m0 + i * 16 + lrow;
        if (rr > M - 1) rr = M - 1;
        Ap[i] = A + (size_t)rr * lda + lk8;
        Bp[i] = Bt + (size_t)(n0 + i * 16 + lrow) * ldb + lk8;
    }

    fvec4 acc[4][4];
    const fvec4 z = {0.f, 0.f, 0.f, 0.f};
    #pragma unroll
    for (int i = 0; i < 4; ++i)
        #pragma unroll
        for (int j = 0; j < 4; ++j) acc[i][j] = z;

    #pragma unroll 2
    for (int k = 0; k < K; k += 32) {
        bvec8 a[4], b[4];
        #pragma unroll
        for (int i = 0; i < 4; ++i) a[i] = *reinterpret_cast<const bvec8*>(Ap[i] + k);
        #pragma unroll
        for (int j = 0; j < 4; ++j) b[j] = *reinterpret_cast<const bvec8*>(Bp[j] + k);
        #pragma unroll
        for (int i = 0; i < 4; ++i)
            #pragma unroll
            for (int j = 0; j < 4; ++j)
                acc[i][j] = mfma16(a[i], b[j], acc[i][j]);
    }

    const int r4 = (lane >> 4) * 4;
    #pragma unroll
    for (int fn = 0; fn < 4; ++fn) {
        const int col = n0 + fn * 16 + lrow;
        if (col < 512) {
            #pragma unroll
            for (int fm = 0; fm < 4; ++fm) {
                const int rbase = m0 + fm * 16 + r4;
                #pragma unroll
                for (int rr = 0; rr < 4; ++rr) {
                    const int row = rbase + rr;
                    if (row >= M) continue;
                    xs[(size_t)row * 512 + col] = __float2bfloat16(acc[fm][fn][rr]);
                }
            }
        } else {
            const int c2 = col - 512;
            const float bz = biasU[c2];
            #pragma unroll
            for (int fm = 0; fm < 4; ++fm) {
                const int rbase = m0 + fm * 16 + r4;
                #pragma unroll
                for (int rr = 0; rr < 4; ++rr) {
                    const int row = rbase + rr;
                    if (row >= M) continue;
                    hB[(size_t)row * 512 + c2] = acc[fm][fn][rr] + bz;
                }
            }
        }
    }
}

// ---------- V tables for both s and d in one dispatch ----------
__global__ void make_v2_kernel(const float* __restrict__ Ws, const float* __restrict__ atts,
                               float* __restrict__ Vs,
                               const float* __restrict__ Wd, const float* __restrict__ attd,
                               float* __restrict__ Vd, int K)
{
    int t = blockIdx.x * blockDim.x + threadIdx.x;
    const int half = K * 4;
    if (t >= 2 * half) return;
    const float* W   = (t < half) ? Ws : Wd;
    const float* att = (t < half) ? atts : attd;
    float* V         = (t < half) ? Vs : Vd;
    int tt = (t < half) ? t : t - half;
    int k = tt >> 2, h = tt & 3;
    float s = 0.f;
    const float* wp = W + (size_t)k * 512 + h * 128;
    const float* ap = att + h * 128;
    #pragma unroll 4
    for (int c = 0; c < 128; ++c)
        s = fmaf(wp[c], ap[c], s);
    V[k * 4 + h] = s;
}

// ---------- fused GAT aggregation: one wave per destination node ----------
__global__ __launch_bounds__(64) void gat_gather_kernel(
    const int* __restrict__ row_ptr, const int* __restrict__ col_src,
    const float* __restrict__ a_s, const float* __restrict__ a_d,
    const bf16* __restrict__ xs, float* __restrict__ hout,
    bf16* __restrict__ hout_bf)
{
    const int d = blockIdx.x, lane = threadIdx.x;
    const int beg = row_ptr[d], end = row_ptr[d + 1];
    const float4 ad = *reinterpret_cast<const float4*>(a_d + (size_t)d * 4);

    float m0=-1e30f, m1=-1e30f, m2=-1e30f, m3=-1e30f;
    for (int i = beg + lane; i < end; i += 64) {
        int s = col_src[i];
        float4 as = *reinterpret_cast<const float4*>(a_s + (size_t)s * 4);
        m0 = fmaxf(m0, lrelu(as.x + ad.x));
        m1 = fmaxf(m1, lrelu(as.y + ad.y));
        m2 = fmaxf(m2, lrelu(as.z + ad.z));
        m3 = fmaxf(m3, lrelu(as.w + ad.w));
    }
    m0 = wred_max(m0); m1 = wred_max(m1); m2 = wred_max(m2); m3 = wred_max(m3);

    float d0=0.f, d1=0.f, d2=0.f, d3=0.f;
    for (int i = beg + lane; i < end; i += 64) {
        int s = col_src[i];
        float4 as = *reinterpret_cast<const float4*>(a_s + (size_t)s * 4);
        d0 += __expf(lrelu(as.x + ad.x) - m0);
        d1 += __expf(lrelu(as.y + ad.y) - m1);
        d2 += __expf(lrelu(as.z + ad.z) - m2);
        d3 += __expf(lrelu(as.w + ad.w) - m3);
    }
    d0 = wred_sum(d0); d1 = wred_sum(d1); d2 = wred_sum(d2); d3 = wred_sum(d3);

    const int h = lane >> 4;
    const float mh   = (h == 0) ? m0 : ((h == 1) ? m1 : ((h == 2) ? m2 : m3));
    const float adh  = (h == 0) ? ad.x : ((h == 1) ? ad.y : ((h == 2) ? ad.z : ad.w));
    const float den  = (h == 0) ? d0 : ((h == 1) ? d1 : ((h == 2) ? d2 : d3));
    const float invd = 1.0f / (den + 1e-16f);
    const int c0 = lane * 8;
    float acc[8] = {0.f,0.f,0.f,0.f,0.f,0.f,0.f,0.f};
    #pragma unroll 2
    for (int i = beg; i < end; ++i) {
        int s = col_src[i];
        float coef = __expf(lrelu(a_s[(size_t)s * 4 + h] + adh) - mh) * invd;
        float xv[8];
        bf8_to_f(xs + (size_t)s * 512 + c0, xv);
        #pragma unroll
        for (int t = 0; t < 8; ++t) acc[t] = fmaf(coef, xv[t], acc[t]);
    }
    float* hp = hout + (size_t)d * 512 + c0;
    if (hout_bf) {
        bf16* hb = hout_bf + (size_t)d * 512 + c0;
        #pragma unroll
        for (int t = 0; t < 8; ++t) {
            float fv = hp[t] + acc[t];
            hp[t] = fv;
            hb[t] = __float2bfloat16(fv);
        }
    } else {
        #pragma unroll
        for (int t = 0; t < 8; ++t) hp[t] += acc[t];
    }
}

// ---------- LN+ReLU -> hA_bf, fused with block-2 logits ----------
__global__ __launch_bounds__(64) void ln_relu_logits_kernel(
    const float* __restrict__ in, const float* __restrict__ g,
    const float* __restrict__ b,
    const float* __restrict__ Vs, const float* __restrict__ Vd,
    bf16* __restrict__ outbf, float* __restrict__ a_s, float* __restrict__ a_d)
{
    const int n = blockIdx.x, lane = threadIdx.x;
    const int c0 = lane * 8;
    const float* ip = in + (size_t)n * 512 + c0;
    float v[8];
    float4 p0 = *reinterpret_cast<const float4*>(ip);
    float4 p1 = *reinterpret_cast<const float4*>(ip + 4);
    v[0]=p0.x; v[1]=p0.y; v[2]=p0.z; v[3]=p0.w; v[4]=p1.x; v[5]=p1.y; v[6]=p1.z; v[7]=p1.w;
    float s = 0.f;
    #pragma unroll
    for (int t = 0; t < 8; ++t) s += v[t];
    s = wred_sum(s);
    const float mu = s * (1.0f / 512.0f);
    float q = 0.f;
    #pragma unroll
    for (int t = 0; t < 8; ++t) { float dlt = v[t] - mu; q = fmaf(dlt, dlt, q); }
    q = wred_sum(q);
    const float sc = rsqrtf(q * (1.0f / 512.0f) + 1e-5f);
    float4 g0 = *reinterpret_cast<const float4*>(g + c0);
    float4 g1 = *reinterpret_cast<const float4*>(g + c0 + 4);
    float4 b0 = *reinterpret_cast<const float4*>(b + c0);
    float4 b1 = *reinterpret_cast<const float4*>(b + c0 + 4);
    const float gv[8] = {g0.x,g0.y,g0.z,g0.w,g1.x,g1.y,g1.z,g1.w};
    const float bv[8] = {b0.x,b0.y,b0.z,b0.w,b1.x,b1.y,b1.z,b1.w};
    float r[8];
    bf16* ob = outbf + (size_t)n * 512 + c0;
    #pragma unroll
    for (int t = 0; t < 8; ++t) {
        r[t] = fmaxf(0.f, fmaf((v[t] - mu) * sc, gv[t], bv[t]));
        ob[t] = __float2bfloat16(r[t]);
    }
    float ss0=0,ss1=0,ss2=0,ss3=0, dd0=0,dd1=0,dd2=0,dd3=0;
    #pragma unroll
    for (int t = 0; t < 8; ++t) {
        float4 vs = *reinterpret_cast<const float4*>(Vs + (size_t)(c0 + t) * 4);
        float4 vd = *reinterpret_cast<const float4*>(Vd + (size_t)(c0 + t) * 4);
        ss0 = fmaf(r[t], vs.x, ss0); ss1 = fmaf(r[t], vs.y, ss1);
        ss2 = fmaf(r[t], vs.z, ss2); ss3 = fmaf(r[t], vs.w, ss3);
        dd0 = fmaf(r[t], vd.x, dd0); dd1 = fmaf(r[t], vd.y, dd1);
        dd2 = fmaf(r[t], vd.z, dd2); dd3 = fmaf(r[t], vd.w, dd3);
    }
    ss0 = wred_sum(ss0); ss1 = wred_sum(ss1); ss2 = wred_sum(ss2); ss3 = wred_sum(ss3);
    dd0 = wred_sum(dd0); dd1 = wred_sum(dd1); dd2 = wred_sum(dd2); dd3 = wred_sum(dd3);
    if (lane == 0) {
        a_s[n*4+0]=ss0; a_s[n*4+1]=ss1; a_s[n*4+2]=ss2; a_s[n*4+3]=ss3;
        a_d[n*4+0]=dd0; a_d[n*4+1]=dd1; a_d[n*4+2]=dd2; a_d[n*4+3]=dd3;
    }
}

// ---------- launcher ----------
extern "C" void kernel_launch(void* const* d_in, const int* in_sizes, int n_in,
                              void* d_out, int out_size, void* d_ws, size_t ws_size,
                              hipStream_t stream)
{
    (void)n_in; (void)out_size; (void)ws_size;
    const float* x   = (const float*)d_in[0];
    const int*   ei  = (const int*)d_in[1];

    const float* W_rna  = (const float*)d_in[2];
    const float* b_rna  = (const float*)d_in[3];
    const float* W_prot = (const float*)d_in[4];
    const float* b_prot = (const float*)d_in[5];
    const float* c1_Ws  = (const float*)d_in[6];
    const float* c1_Wd  = (const float*)d_in[7];
    const float* c1_as  = (const float*)d_in[8];
    const float* c1_ad  = (const float*)d_in[9];
    const float* c1_b   = (const float*)d_in[10];
    const float* l1_W   = (const float*)d_in[11];
    const float* l1_b   = (const float*)d_in[12];
    const float* ln_g   = (const float*)d_in[13];
    const float* ln_b   = (const float*)d_in[14];
    const float* c2_Ws  = (const float*)d_in[15];
    const float* c2_Wd  = (const float*)d_in[16];
    const float* c2_as  = (const float*)d_in[17];
    const float* c2_ad  = (const float*)d_in[18];
    const float* c2_b   = (const float*)d_in[19];
    const float* l2_W   = (const float*)d_in[20];
    const float* l2_b   = (const float*)d_in[21];
    const float* agg_W  = (const float*)d_in[22];
    const float* agg_b  = (const float*)d_in[23];
    const float* dr_W   = (const float*)d_in[24];
    const float* dr_b   = (const float*)d_in[25];
    const float* dp_W   = (const float*)d_in[26];
    const float* dp_b   = (const float*)d_in[27];
    const float* rr_W   = (const float*)d_in[28];
    const float* rr_b   = (const float*)d_in[29];
    const float* rp_W   = (const float*)d_in[30];
    const float* rp_b   = (const float*)d_in[31];

    const int N = in_sizes[0] / 2100;   // 10000
    const int E = in_sizes[1] / 2;      // 160000
    const int Mp = ((N + 127) & ~127) + 128;

    char* wsp = (char*)d_ws;
    size_t off = 0;
    auto alloc = [&](size_t bytes) -> void* {
        void* p = wsp + off;
        off += (bytes + 255) & ~(size_t)255;
        return p;
    };
    int*      flags   = (int*)   alloc(16);
    int*      src32   = (int*)   alloc((size_t)E * 4);
    int*      dst32   = (int*)   alloc((size_t)E * 4);
    int*      cnt     = (int*)   alloc((size_t)N * 4);
    int*      cursor  = (int*)   alloc((size_t)N * 4);
    int*      row_ptr = (int*)   alloc((size_t)(N + 1) * 4);
    int*      col_src = (int*)   alloc((size_t)E * 4);
    float*    hB      = (float*) alloc((size_t)N * 512 * 4);
    float*    a_s     = (float*) alloc((size_t)N * 4 * 4);
    float*    a_d     = (float*) alloc((size_t)N * 4 * 4);
    float*    Vs      = (float*) alloc(512 * 4 * 4);
    float*    Vd      = (float*) alloc(512 * 4 * 4);
    float*    bsum1   = (float*) alloc(512 * 4);
    float*    bsum2   = (float*) alloc(512 * 4);
    float*    ddb     = (float*) alloc(256 * 4);
    // bf16 activation buffers (row-padded to Mp)
    bf16*     xbf     = (bf16*)  alloc((size_t)Mp * 2128 * 2);
    bf16*     xin_bf  = (bf16*)  alloc((size_t)Mp * 256 * 2);
    bf16*     hA_bf   = (bf16*)  alloc((size_t)Mp * 512 * 2);
    bf16*     hB_bf   = (bf16*)  alloc((size_t)Mp * 512 * 2);
    bf16*     xs      = (bf16*)  alloc((size_t)Mp * 512 * 2);
    bf16*     emb_bf  = (bf16*)  alloc((size_t)Mp * 128 * 2);
    bf16*     trp     = (bf16*)  alloc((size_t)Mp * 256 * 2);
    // bf16 transposed weights
    bf16*     wrna_t  = (bf16*)  alloc((size_t)128 * 2016 * 2);
    bf16*     wprot_t = (bf16*)  alloc((size_t)128 * 128 * 2);
    bf16*     cb1     = (bf16*)  alloc((size_t)1024 * 256 * 2);   // [c1t ; l1t]
    bf16*     cb2     = (bf16*)  alloc((size_t)1024 * 512 * 2);   // [c2t ; l2t]
    bf16*     aggt    = (bf16*)  alloc((size_t)128 * 512 * 2);
    bf16*     ddt     = (bf16*)  alloc((size_t)256 * 128 * 2);    // [drt ; dpt]
    bf16*     rrt     = (bf16*)  alloc((size_t)2048 * 128 * 2);
    bf16*     rpt     = (bf16*)  alloc((size_t)128 * 128 * 2);

    const dim3 blk64(64, 1, 1);
    const dim3 blk256(256, 1, 1);
    const dim3 blk512(512, 1, 1);
    const dim3 gE((E + 255) / 256);
    const dim3 gN((N + 255) / 256);
    const int GY128 = (N + 127) / 128;   // 79
    const int GY64  = (N + 63) / 64;     // 157
    const int GY32  = (N + 31) / 32;     // 313
    const int NWG_DUAL = GY128 * 4;      // 316 (128-row strips x 4 col-blocks of 256)

    float* out0 = (float*)d_out;
    float* out1 = out0 + (size_t)N * 2000;
    float* out2 = out1 + (size_t)N * 100;

    // ---- edges -> CSR by dst ----
    detect_kernel<<<dim3(1), blk256, 0, stream>>>(ei, E, flags);
    conv_edges_kernel<<<gE, blk256, 0, stream>>>(ei, src32, dst32, E, N, flags);
    zero2_kernel<<<gN, blk256, 0, stream>>>(cnt, cursor, N);
    hist_kernel<<<gE, blk256, 0, stream>>>(dst32, cnt, E);
    scan_kernel<<<dim3(1), dim3(1024, 1, 1), 0, stream>>>(cnt, row_ptr, N);
    fill_csr_kernel<<<gE, blk256, 0, stream>>>(src32, dst32, row_ptr, cursor, col_src, E);

    // ---- weight converts (LDS-tiled transpose, one dispatch) ----
    {
        TTab tab{};
        int nt = 0, i = 0;
        auto add = [&](const float* s, bf16* d, int K, int Nn, int Kp, int Np) {
            tab.e[i] = {s, d, K, Nn, Kp, Np, nt};
            nt += (Kp >> 5) * (Np >> 5);
            ++i;
        };
        add(W_rna,  wrna_t,          2000, 128, 2016, 128);
        add(W_prot, wprot_t,          100, 128,  128, 128);
        add(c1_Ws,  cb1,              256, 512,  256, 512);
        add(l1_W,   cb1 + 512 * 256,  256, 512,  256, 512);
        add(c2_Ws,  cb2,              512, 512,  512, 512);
        add(l2_W,   cb2 + 512 * 512,  512, 512,  512, 512);
        add(agg_W,  aggt,             512, 128,  512, 128);
        add(dr_W,   ddt,              128, 128,  128, 128);
        add(dp_W,   ddt + 128 * 128,  128, 128,  128, 128);
        add(rr_W,   rrt,              128, 2000, 128, 2048);
        add(rp_W,   rpt,              128, 100,  128, 128);
        tab.n = i;
        wconv_t_kernel<<<dim3(nt), blk256, 0, stream>>>(tab);
    }
    bias_fuse_kernel<<<dim3(5), blk256, 0, stream>>>(l1_b, c1_b, bsum1,
                                                     l2_b, c2_b, bsum2,
                                                     dr_b, dp_b, ddb);
    make_v2_kernel<<<dim3((2 * 256 * 4 + 255) / 256), blk256, 0, stream>>>(
        c1_Ws, c1_as, Vs, c1_Wd, c1_ad, Vd, 256);

    // ---- x -> bf16 once (streaming, vectorized), then bf16-A embed GEMMs ----
    conv_x_kernel<<<dim3(N), blk256, 0, stream>>>(x, xbf);
    mfma_gemm_kernel<2, false, bf16><<<dim3(2, GY64), blk256, 0, stream>>>(
        xbf, 2128, wrna_t, 2016, b_rna, nullptr, 0, xin_bf, 256, N, 128, 2016);
    mfma_gemm_kernel<1, false, bf16><<<dim3(2, GY32), blk256, 0, stream>>>(
        xbf + 2000, 2128, wprot_t, 128, b_prot, nullptr, 0, xin_bf + 128, 256, N, 128, 128);
    logits_bf16_kernel<<<dim3(N), blk64, 0, stream>>>(xin_bf, Vs, Vd, a_s, a_d);

    // ---- block 1 ----
    mfma_gemm_dual_kernel<<<dim3(NWG_DUAL), blk512, 0, stream>>>(
        xin_bf, 256, cb1, 256, bsum1, xs, hB, N, 256, NWG_DUAL);
    gat_gather_kernel<<<dim3(N), blk64, 0, stream>>>(row_ptr, col_src, a_s, a_d, xs, hB, nullptr);

    // ---- block 2 prep ----
    make_v2_kernel<<<dim3((2 * 512 * 4 + 255) / 256), blk256, 0, stream>>>(
        c2_Ws, c2_as, Vs, c2_Wd, c2_ad, Vd, 512);
    ln_relu_logits_kernel<<<dim3(N), blk64, 0, stream>>>(
        hB, ln_g, ln_b, Vs, Vd, hA_bf, a_s, a_d);

    // ---- block 2 ----
    mfma_gemm_dual_kernel<<<dim3(NWG_DUAL), blk512, 0, stream>>>(
        hA_bf, 512, cb2, 512, bsum2, xs, hB, N, 512, NWG_DUAL);
    gat_gather_kernel<<<dim3(N), blk64, 0, stream>>>(row_ptr, col_src, a_s, a_d, xs, hB, hB_bf);

    // ---- head (all MFMA) ----
    mfma_gemm_kernel<2, true, bf16><<<dim3(2, GY64), blk256, 0, stream>>>(
        hB_bf, 512, aggt, 512, agg_b, out2, 128, emb_bf, 128, N, 128, 512);
    mfma_gemm_kernel<2, false, bf16><<<dim3(4, GY64), blk256, 0, stream>>>(
        emb_bf, 128, ddt, 128, ddb, nullptr, 0, trp, 256, N, 256, 128);
    mfma_gemm_kernel<4, false, bf16><<<dim3(32, GY128), blk256, 0, stream>>>(
        trp, 256, rrt, 128, rr_b, out0, 2000, nullptr, 0, N, 2000, 128);
    mfma_gemm_kernel<2, false, bf16><<<dim3(2, GY64), blk256, 0, stream>>>(
        trp + 128, 256, rpt, 128, rp_b, out1, 100, nullptr, 0, N, 100, 128);
}

// Round 14
// 588.740 us; speedup vs baseline: 1.0279x; 1.0279x over previous
//
#include <hip/hip_runtime.h>
#include <hip/hip_bf16.h>
#include <stdint.h>
#include <stddef.h>

using bf16  = __hip_bfloat16;
using bf162 = __hip_bfloat162;

typedef __bf16 bvec8 __attribute__((ext_vector_type(8)));
typedef float  fvec4 __attribute__((ext_vector_type(4)));

// ---------- helpers ----------
struct __align__(16) bf16x8 { bf162 a, b, c, d; };

__device__ __forceinline__ void bf8_to_f(const bf16* p, float* o) {
    bf16x8 v = *reinterpret_cast<const bf16x8*>(p);
    o[0] = __bfloat162float(v.a.x); o[1] = __bfloat162float(v.a.y);
    o[2] = __bfloat162float(v.b.x); o[3] = __bfloat162float(v.b.y);
    o[4] = __bfloat162float(v.c.x); o[5] = __bfloat162float(v.c.y);
    o[6] = __bfloat162float(v.d.x); o[7] = __bfloat162float(v.d.y);
}

__device__ __forceinline__ float wred_sum(float v) {
    #pragma unroll
    for (int o = 32; o > 0; o >>= 1) v += __shfl_xor(v, o);
    return v;
}

__device__ __forceinline__ float wred_max(float v) {
    #pragma unroll
    for (int o = 32; o > 0; o >>= 1) v = fmaxf(v, __shfl_xor(v, o));
    return v;
}

__device__ __forceinline__ float lrelu(float x) { return (x > 0.f) ? x : 0.2f * x; }

__device__ __forceinline__ fvec4 mfma16(bvec8 a, bvec8 b, fvec4 c) {
    return __builtin_amdgcn_mfma_f32_16x16x32_bf16(a, b, c, 0, 0, 0);
}

__device__ __forceinline__ bvec8 ldA(const bf16* p) {
    return *reinterpret_cast<const bvec8*>(p);
}
__device__ __forceinline__ bvec8 ldA(const float* p) {
    float4 f0 = *reinterpret_cast<const float4*>(p);
    float4 f1 = *reinterpret_cast<const float4*>(p + 4);
    union { bvec8 v; bf16 h[8]; } u;
    u.h[0] = __float2bfloat16(f0.x); u.h[1] = __float2bfloat16(f0.y);
    u.h[2] = __float2bfloat16(f0.z); u.h[3] = __float2bfloat16(f0.w);
    u.h[4] = __float2bfloat16(f1.x); u.h[5] = __float2bfloat16(f1.y);
    u.h[6] = __float2bfloat16(f1.z); u.h[7] = __float2bfloat16(f1.w);
    return u.v;
}

// ---------- edge dtype detection ----------
__global__ void detect_kernel(const int* __restrict__ ei, int E, int* __restrict__ flags) {
    __shared__ int zc;
    if (threadIdx.x == 0) zc = 0;
    __syncthreads();
    int nodd = E / 2; if (nodd > 1024) nodd = 1024;
    for (int i = threadIdx.x; i < nodd; i += blockDim.x)
        if (ei[2 * i + 1] == 0) atomicAdd(&zc, 1);
    __syncthreads();
    if (threadIdx.x == 0) flags[0] = (zc > nodd / 2) ? 1 : 0;
}

__global__ void conv_edges_kernel(const int* __restrict__ ei, int* __restrict__ src32,
                                  int* __restrict__ dst32, int E, int N,
                                  const int* __restrict__ flags) {
    const int e = blockIdx.x * blockDim.x + threadIdx.x;
    if (e >= E) return;
    int s, d;
    if (flags[0]) { s = ei[2 * e]; d = ei[2 * (E + e)]; }
    else          { s = ei[e];     d = ei[E + e]; }
    src32[e] = (s < 0) ? 0 : ((s >= N) ? N - 1 : s);
    dst32[e] = (d < 0) ? 0 : ((d >= N) ? N - 1 : d);
}

// ---------- CSR build ----------
__global__ void zero2_kernel(int* __restrict__ p1, int* __restrict__ p2, int n) {
    int i = blockIdx.x * blockDim.x + threadIdx.x;
    if (i < n) { p1[i] = 0; p2[i] = 0; }
}

__global__ void hist_kernel(const int* __restrict__ dst32, int* __restrict__ cnt, int E) {
    int e = blockIdx.x * blockDim.x + threadIdx.x;
    if (e < E) atomicAdd(&cnt[dst32[e]], 1);
}

// 16-wave shfl-based exclusive scan: cnt[0..N) -> row_ptr[0..N]
__global__ __launch_bounds__(1024) void scan_kernel(const int* __restrict__ cnt,
                                                    int* __restrict__ row_ptr, int N) {
    __shared__ int wsum[16];
    __shared__ int carry;
    const int tid = threadIdx.x, lane = tid & 63, wid = tid >> 6;
    if (tid == 0) { carry = 0; row_ptr[0] = 0; }
    __syncthreads();
    for (int base = 0; base < N; base += 1024) {
        int i = base + tid;
        int v = (i < N) ? cnt[i] : 0;
        int s = v;
        #pragma unroll
        for (int o = 1; o < 64; o <<= 1) {
            int t = __shfl_up(s, o);
            if (lane >= o) s += t;
        }
        if (lane == 63) wsum[wid] = s;
        __syncthreads();
        if (wid == 0 && lane < 16) {
            int ws = wsum[lane];
            #pragma unroll
            for (int o = 1; o < 16; o <<= 1) {
                int t = __shfl_up(ws, o);
                if (lane >= o) ws += t;
            }
            wsum[lane] = ws;
        }
        __syncthreads();
        int add = carry + (wid > 0 ? wsum[wid - 1] : 0);
        if (i < N) row_ptr[i + 1] = s + add;
        __syncthreads();
        if (tid == 0) carry += wsum[15];
        __syncthreads();
    }
}

__global__ void fill_csr_kernel(const int* __restrict__ src32, const int* __restrict__ dst32,
                                const int* __restrict__ row_ptr, int* __restrict__ cursor,
                                int* __restrict__ col_src, int E) {
    int e = blockIdx.x * blockDim.x + threadIdx.x;
    if (e >= E) return;
    int d = dst32[e];
    int pos = atomicAdd(&cursor[d], 1);
    col_src[row_ptr[d] + pos] = src32[e];
}

// ---------- all weight converts, LDS-tiled transpose (coalesced both sides) ----------
struct TEnt { const float* src; bf16* dst; int K, N, Kp, Np, tstart; };
struct TTab { TEnt e[12]; int n; };

__global__ __launch_bounds__(256) void wconv_t_kernel(TTab tab) {
    __shared__ float tile[32][33];
    const int b = blockIdx.x;
    int wi = 0;
    #pragma unroll 1
    for (int i = 1; i < tab.n; ++i) if (b >= tab.e[i].tstart) wi = i;
    const TEnt w = tab.e[wi];
    const int tidx = b - w.tstart;
    const int ntk = w.Kp >> 5;
    const int tn = tidx / ntk, tk = tidx - tn * ntk;
    const int k0 = tk * 32, n0 = tn * 32;
    const int tx = threadIdx.x & 31, ty = threadIdx.x >> 5;   // 32 x 8
    #pragma unroll
    for (int j = 0; j < 4; ++j) {
        int k = k0 + ty * 4 + j;
        int n = n0 + tx;
        tile[ty * 4 + j][tx] = (k < w.K && n < w.N) ? w.src[(size_t)k * w.N + n] : 0.f;
    }
    __syncthreads();
    #pragma unroll
    for (int j = 0; j < 4; ++j) {
        int n = n0 + ty * 4 + j;
        int k = k0 + tx;
        w.dst[(size_t)n * w.Kp + k] = __float2bfloat16(tile[tx][ty * 4 + j]);
    }
}

// ---------- x -> bf16, row stride 2128, fully vectorized ----------
__global__ __launch_bounds__(256) void conv_x_kernel(const float* __restrict__ x,
                                                     bf16* __restrict__ xbf) {
    const int r = blockIdx.x;
    const float* xr = x + (size_t)r * 2100;
    bf16* orow = xbf + (size_t)r * 2128;
    #pragma unroll
    for (int pass = 0; pass < 2; ++pass) {
        int c0 = pass * 2048 + threadIdx.x * 8;
        if (c0 >= 2128) continue;
        union { uint4 u; bf16 h[8]; } ob;
        if (c0 + 8 <= 2100) {
            float4 f0 = *reinterpret_cast<const float4*>(xr + c0);
            float4 f1 = *reinterpret_cast<const float4*>(xr + c0 + 4);
            ob.h[0] = __float2bfloat16(f0.x); ob.h[1] = __float2bfloat16(f0.y);
            ob.h[2] = __float2bfloat16(f0.z); ob.h[3] = __float2bfloat16(f0.w);
            ob.h[4] = __float2bfloat16(f1.x); ob.h[5] = __float2bfloat16(f1.y);
            ob.h[6] = __float2bfloat16(f1.z); ob.h[7] = __float2bfloat16(f1.w);
        } else {
            #pragma unroll
            for (int j = 0; j < 8; ++j) {
                int c = c0 + j;
                ob.h[j] = __float2bfloat16((c < 2100) ? xr[c] : 0.f);
            }
        }
        *reinterpret_cast<uint4*>(orow + c0) = ob.u;
    }
}

// ---------- fused bias prep ----------
__global__ void bias_fuse_kernel(const float* l1_b, const float* c1_b, float* bsum1,
                                 const float* l2_b, const float* c2_b, float* bsum2,
                                 const float* dr_b, const float* dp_b, float* ddb) {
    int i = blockIdx.x * blockDim.x + threadIdx.x;
    if (i < 512)       bsum1[i] = l1_b[i] + c1_b[i];
    else if (i < 1024) bsum2[i - 512] = l2_b[i - 512] + c2_b[i - 512];
    else if (i < 1152) ddb[i - 1024] = dr_b[i - 1024];
    else if (i < 1280) ddb[i - 1024] = dp_b[i - 1152];
}

// ---------- block-1 logits from xin_bf: one wave per node, K=256 ----------
__global__ __launch_bounds__(64) void logits_bf16_kernel(
    const bf16* __restrict__ X,
    const float* __restrict__ Vs, const float* __restrict__ Vd,
    float* __restrict__ a_s, float* __restrict__ a_d)
{
    const int n = blockIdx.x, lane = threadIdx.x;
    const int c0 = lane * 4;
    union { uint2 u; bf16 h[4]; } ub;
    ub.u = *reinterpret_cast<const uint2*>(X + (size_t)n * 256 + c0);
    const float vv[4] = {__bfloat162float(ub.h[0]), __bfloat162float(ub.h[1]),
                         __bfloat162float(ub.h[2]), __bfloat162float(ub.h[3])};
    float ss0=0,ss1=0,ss2=0,ss3=0, dd0=0,dd1=0,dd2=0,dd3=0;
    #pragma unroll
    for (int j = 0; j < 4; ++j) {
        float4 vs = *reinterpret_cast<const float4*>(Vs + (size_t)(c0 + j) * 4);
        float4 vd = *reinterpret_cast<const float4*>(Vd + (size_t)(c0 + j) * 4);
        ss0 = fmaf(vv[j], vs.x, ss0); ss1 = fmaf(vv[j], vs.y, ss1);
        ss2 = fmaf(vv[j], vs.z, ss2); ss3 = fmaf(vv[j], vs.w, ss3);
        dd0 = fmaf(vv[j], vd.x, dd0); dd1 = fmaf(vv[j], vd.y, dd1);
        dd2 = fmaf(vv[j], vd.z, dd2); dd3 = fmaf(vv[j], vd.w, dd3);
    }
    ss0 = wred_sum(ss0); ss1 = wred_sum(ss1); ss2 = wred_sum(ss2); ss3 = wred_sum(ss3);
    dd0 = wred_sum(dd0); dd1 = wred_sum(dd1); dd2 = wred_sum(dd2); dd3 = wred_sum(dd3);
    if (lane == 0) {
        a_s[n*4+0]=ss0; a_s[n*4+1]=ss1; a_s[n*4+2]=ss2; a_s[n*4+3]=ss3;
        a_d[n*4+0]=dd0; a_d[n*4+1]=dd1; a_d[n*4+2]=dd2; a_d[n*4+3]=dd3;
    }
}

// ---------- MFMA GEMM: C[M,Nn] = A[M,K] @ Bt[Nn,K]^T (+bias, relu) ----------
template <int FM, bool RELU, typename AT>
__global__ __launch_bounds__(256) void mfma_gemm_kernel(
    const AT* __restrict__ A, int lda,
    const bf16* __restrict__ Bt, int ldb,
    const float* __restrict__ bias,
    float* __restrict__ Cf, int ldcf,
    bf16* __restrict__ Cb, int ldcb,
    int M, int Nn, int K)
{
    const int tid  = threadIdx.x;
    const int w    = tid >> 6, lane = tid & 63;
    const int wr   = w >> 1,   wc   = w & 1;
    const int m0   = blockIdx.y * (FM * 32) + wr * (FM * 16);
    const int n0   = blockIdx.x * 64 + wc * 32;
    const int lrow = lane & 15;
    const int lk8  = (lane >> 4) * 8;

    const AT* Ap[FM];
    #pragma unroll
    for (int i = 0; i < FM; ++i) {
        int r = m0 + i * 16 + lrow;
        if (r > M - 1) r = M - 1;
        Ap[i] = A + (size_t)r * lda + lk8;
    }
    const bf16* Bp = Bt + (size_t)(n0 + lrow) * ldb + lk8;
    const size_t b16 = (size_t)16 * ldb;

    fvec4 acc[FM][2];
    const fvec4 z = {0.f, 0.f, 0.f, 0.f};
    #pragma unroll
    for (int i = 0; i < FM; ++i) { acc[i][0] = z; acc[i][1] = z; }

    #pragma unroll 2
    for (int k = 0; k < K; k += 32) {
        bvec8 b0 = *reinterpret_cast<const bvec8*>(Bp + k);
        bvec8 b1 = *reinterpret_cast<const bvec8*>(Bp + k + b16);
        #pragma unroll
        for (int i = 0; i < FM; ++i) {
            bvec8 a = ldA(Ap[i] + k);
            acc[i][0] = mfma16(a, b0, acc[i][0]);
            acc[i][1] = mfma16(a, b1, acc[i][1]);
        }
    }

    const int r4 = (lane >> 4) * 4;
    #pragma unroll
    for (int fn = 0; fn < 2; ++fn) {
        const int col = n0 + fn * 16 + lrow;
        if (col >= Nn) continue;
        const float bz = bias ? bias[col] : 0.f;
        #pragma unroll
        for (int fm = 0; fm < FM; ++fm) {
            const int rbase = m0 + fm * 16 + r4;
            #pragma unroll
            for (int r = 0; r < 4; ++r) {
                const int row = rbase + r;
                if (row >= M) continue;
                float v = acc[fm][fn][r] + bz;
                if (RELU) v = fmaxf(v, 0.f);
                if (Cf) Cf[(size_t)row * ldcf + col] = v;
                if (Cb) Cb[(size_t)row * ldcb + col] = __float2bfloat16(v);
            }
        }
    }
}

// ---------- dual-output MFMA GEMM, 128x128 block, 4 waves, wave tile 64x64 ----------
// 1D grid, bijective chunked XCD swizzle: 8 col-blocks of each 128-row strip
// stay inside one XCD's chunk -> A panel cached in that XCD's L2.
// cols 0..511 -> xs (bf16), 512..1023 -> hB (f32)+bias.
__global__ __launch_bounds__(256) void mfma_gemm_dual_kernel(
    const bf16* __restrict__ A, int lda,
    const bf16* __restrict__ Bt, int ldb,
    const float* __restrict__ biasU,
    bf16* __restrict__ xs, float* __restrict__ hB,
    int M, int K, int nwg)
{
    // hardware bid -> logical tile id, chunked per XCD (m204 bijective)
    const int bid = blockIdx.x;
    const int q = nwg >> 3, r = nwg & 7;
    const int xcd = bid & 7, idx = bid >> 3;
    const int sbid = (xcd < r ? xcd * (q + 1) : r * (q + 1) + (xcd - r) * q) + idx;
    const int by = sbid >> 3, bx = sbid & 7;

    const int tid  = threadIdx.x;
    const int w    = tid >> 6, lane = tid & 63;
    const int wr   = w >> 1,   wc   = w & 1;
    const int m0   = by * 128 + wr * 64;
    const int n0   = bx * 128 + wc * 64;
    const int lrow = lane & 15;
    const int lk8  = (lane >> 4) * 8;

    const bf16* Ap[4];
    const bf16* Bp[4];
    #pragma unroll
    for (int i = 0; i < 4; ++i) {
        int rr = m0 + i * 16 + lrow;
        if (rr > M - 1) rr = M - 1;
        Ap[i] = A + (size_t)rr * lda + lk8;
        Bp[i] = Bt + (size_t)(n0 + i * 16 + lrow) * ldb + lk8;
    }

    fvec4 acc[4][4];
    const fvec4 z = {0.f, 0.f, 0.f, 0.f};
    #pragma unroll
    for (int i = 0; i < 4; ++i)
        #pragma unroll
        for (int j = 0; j < 4; ++j) acc[i][j] = z;

    #pragma unroll 2
    for (int k = 0; k < K; k += 32) {
        bvec8 a[4], b[4];
        #pragma unroll
        for (int i = 0; i < 4; ++i) a[i] = *reinterpret_cast<const bvec8*>(Ap[i] + k);
        #pragma unroll
        for (int j = 0; j < 4; ++j) b[j] = *reinterpret_cast<const bvec8*>(Bp[j] + k);
        #pragma unroll
        for (int i = 0; i < 4; ++i)
            #pragma unroll
            for (int j = 0; j < 4; ++j)
                acc[i][j] = mfma16(a[i], b[j], acc[i][j]);
    }

    const int r4 = (lane >> 4) * 4;
    #pragma unroll
    for (int fn = 0; fn < 4; ++fn) {
        const int col = n0 + fn * 16 + lrow;
        if (col < 512) {
            #pragma unroll
            for (int fm = 0; fm < 4; ++fm) {
                const int rbase = m0 + fm * 16 + r4;
                #pragma unroll
                for (int rr = 0; rr < 4; ++rr) {
                    const int row = rbase + rr;
                    if (row >= M) continue;
                    xs[(size_t)row * 512 + col] = __float2bfloat16(acc[fm][fn][rr]);
                }
            }
        } else {
            const int c2 = col - 512;
            const float bz = biasU[c2];
            #pragma unroll
            for (int fm = 0; fm < 4; ++fm) {
                const int rbase = m0 + fm * 16 + r4;
                #pragma unroll
                for (int rr = 0; rr < 4; ++rr) {
                    const int row = rbase + rr;
                    if (row >= M) continue;
                    hB[(size_t)row * 512 + c2] = acc[fm][fn][rr] + bz;
                }
            }
        }
    }
}

// ---------- V tables for both s and d in one dispatch ----------
__global__ void make_v2_kernel(const float* __restrict__ Ws, const float* __restrict__ atts,
                               float* __restrict__ Vs,
                               const float* __restrict__ Wd, const float* __restrict__ attd,
                               float* __restrict__ Vd, int K)
{
    int t = blockIdx.x * blockDim.x + threadIdx.x;
    const int half = K * 4;
    if (t >= 2 * half) return;
    const float* W   = (t < half) ? Ws : Wd;
    const float* att = (t < half) ? atts : attd;
    float* V         = (t < half) ? Vs : Vd;
    int tt = (t < half) ? t : t - half;
    int k = tt >> 2, h = tt & 3;
    float s = 0.f;
    const float* wp = W + (size_t)k * 512 + h * 128;
    const float* ap = att + h * 128;
    #pragma unroll 4
    for (int c = 0; c < 128; ++c)
        s = fmaf(wp[c], ap[c], s);
    V[k * 4 + h] = s;
}

// ---------- fused GAT aggregation: one wave per destination node ----------
__global__ __launch_bounds__(64) void gat_gather_kernel(
    const int* __restrict__ row_ptr, const int* __restrict__ col_src,
    const float* __restrict__ a_s, const float* __restrict__ a_d,
    const bf16* __restrict__ xs, float* __restrict__ hout,
    bf16* __restrict__ hout_bf)
{
    const int d = blockIdx.x, lane = threadIdx.x;
    const int beg = row_ptr[d], end = row_ptr[d + 1];
    const float4 ad = *reinterpret_cast<const float4*>(a_d + (size_t)d * 4);

    float m0=-1e30f, m1=-1e30f, m2=-1e30f, m3=-1e30f;
    for (int i = beg + lane; i < end; i += 64) {
        int s = col_src[i];
        float4 as = *reinterpret_cast<const float4*>(a_s + (size_t)s * 4);
        m0 = fmaxf(m0, lrelu(as.x + ad.x));
        m1 = fmaxf(m1, lrelu(as.y + ad.y));
        m2 = fmaxf(m2, lrelu(as.z + ad.z));
        m3 = fmaxf(m3, lrelu(as.w + ad.w));
    }
    m0 = wred_max(m0); m1 = wred_max(m1); m2 = wred_max(m2); m3 = wred_max(m3);

    float d0=0.f, d1=0.f, d2=0.f, d3=0.f;
    for (int i = beg + lane; i < end; i += 64) {
        int s = col_src[i];
        float4 as = *reinterpret_cast<const float4*>(a_s + (size_t)s * 4);
        d0 += __expf(lrelu(as.x + ad.x) - m0);
        d1 += __expf(lrelu(as.y + ad.y) - m1);
        d2 += __expf(lrelu(as.z + ad.z) - m2);
        d3 += __expf(lrelu(as.w + ad.w) - m3);
    }
    d0 = wred_sum(d0); d1 = wred_sum(d1); d2 = wred_sum(d2); d3 = wred_sum(d3);

    const int h = lane >> 4;
    const float mh   = (h == 0) ? m0 : ((h == 1) ? m1 : ((h == 2) ? m2 : m3));
    const float adh  = (h == 0) ? ad.x : ((h == 1) ? ad.y : ((h == 2) ? ad.z : ad.w));
    const float den  = (h == 0) ? d0 : ((h == 1) ? d1 : ((h == 2) ? d2 : d3));
    const float invd = 1.0f / (den + 1e-16f);
    const int c0 = lane * 8;
    float acc[8] = {0.f,0.f,0.f,0.f,0.f,0.f,0.f,0.f};
    #pragma unroll 2
    for (int i = beg; i < end; ++i) {
        int s = col_src[i];
        float coef = __expf(lrelu(a_s[(size_t)s * 4 + h] + adh) - mh) * invd;
        float xv[8];
        bf8_to_f(xs + (size_t)s * 512 + c0, xv);
        #pragma unroll
        for (int t = 0; t < 8; ++t) acc[t] = fmaf(coef, xv[t], acc[t]);
    }
    float* hp = hout + (size_t)d * 512 + c0;
    if (hout_bf) {
        bf16* hb = hout_bf + (size_t)d * 512 + c0;
        #pragma unroll
        for (int t = 0; t < 8; ++t) {
            float fv = hp[t] + acc[t];
            hp[t] = fv;
            hb[t] = __float2bfloat16(fv);
        }
    } else {
        #pragma unroll
        for (int t = 0; t < 8; ++t) hp[t] += acc[t];
    }
}

// ---------- LN+ReLU -> hA_bf, fused with block-2 logits ----------
__global__ __launch_bounds__(64) void ln_relu_logits_kernel(
    const float* __restrict__ in, const float* __restrict__ g,
    const float* __restrict__ b,
    const float* __restrict__ Vs, const float* __restrict__ Vd,
    bf16* __restrict__ outbf, float* __restrict__ a_s, float* __restrict__ a_d)
{
    const int n = blockIdx.x, lane = threadIdx.x;
    const int c0 = lane * 8;
    const float* ip = in + (size_t)n * 512 + c0;
    float v[8];
    float4 p0 = *reinterpret_cast<const float4*>(ip);
    float4 p1 = *reinterpret_cast<const float4*>(ip + 4);
    v[0]=p0.x; v[1]=p0.y; v[2]=p0.z; v[3]=p0.w; v[4]=p1.x; v[5]=p1.y; v[6]=p1.z; v[7]=p1.w;
    float s = 0.f;
    #pragma unroll
    for (int t = 0; t < 8; ++t) s += v[t];
    s = wred_sum(s);
    const float mu = s * (1.0f / 512.0f);
    float q = 0.f;
    #pragma unroll
    for (int t = 0; t < 8; ++t) { float dlt = v[t] - mu; q = fmaf(dlt, dlt, q); }
    q = wred_sum(q);
    const float sc = rsqrtf(q * (1.0f / 512.0f) + 1e-5f);
    float4 g0 = *reinterpret_cast<const float4*>(g + c0);
    float4 g1 = *reinterpret_cast<const float4*>(g + c0 + 4);
    float4 b0 = *reinterpret_cast<const float4*>(b + c0);
    float4 b1 = *reinterpret_cast<const float4*>(b + c0 + 4);
    const float gv[8] = {g0.x,g0.y,g0.z,g0.w,g1.x,g1.y,g1.z,g1.w};
    const float bv[8] = {b0.x,b0.y,b0.z,b0.w,b1.x,b1.y,b1.z,b1.w};
    float r[8];
    bf16* ob = outbf + (size_t)n * 512 + c0;
    #pragma unroll
    for (int t = 0; t < 8; ++t) {
        r[t] = fmaxf(0.f, fmaf((v[t] - mu) * sc, gv[t], bv[t]));
        ob[t] = __float2bfloat16(r[t]);
    }
    float ss0=0,ss1=0,ss2=0,ss3=0, dd0=0,dd1=0,dd2=0,dd3=0;
    #pragma unroll
    for (int t = 0; t < 8; ++t) {
        float4 vs = *reinterpret_cast<const float4*>(Vs + (size_t)(c0 + t) * 4);
        float4 vd = *reinterpret_cast<const float4*>(Vd + (size_t)(c0 + t) * 4);
        ss0 = fmaf(r[t], vs.x, ss0); ss1 = fmaf(r[t], vs.y, ss1);
        ss2 = fmaf(r[t], vs.z, ss2); ss3 = fmaf(r[t], vs.w, ss3);
        dd0 = fmaf(r[t], vd.x, dd0); dd1 = fmaf(r[t], vd.y, dd1);
        dd2 = fmaf(r[t], vd.z, dd2); dd3 = fmaf(r[t], vd.w, dd3);
    }
    ss0 = wred_sum(ss0); ss1 = wred_sum(ss1); ss2 = wred_sum(ss2); ss3 = wred_sum(ss3);
    dd0 = wred_sum(dd0); dd1 = wred_sum(dd1); dd2 = wred_sum(dd2); dd3 = wred_sum(dd3);
    if (lane == 0) {
        a_s[n*4+0]=ss0; a_s[n*4+1]=ss1; a_s[n*4+2]=ss2; a_s[n*4+3]=ss3;
        a_d[n*4+0]=dd0; a_d[n*4+1]=dd1; a_d[n*4+2]=dd2; a_d[n*4+3]=dd3;
    }
}

// ---------- launcher ----------
extern "C" void kernel_launch(void* const* d_in, const int* in_sizes, int n_in,
                              void* d_out, int out_size, void* d_ws, size_t ws_size,
                              hipStream_t stream)
{
    (void)n_in; (void)out_size; (void)ws_size;
    const float* x   = (const float*)d_in[0];
    const int*   ei  = (const int*)d_in[1];

    const float* W_rna  = (const float*)d_in[2];
    const float* b_rna  = (const float*)d_in[3];
    const float* W_prot = (const float*)d_in[4];
    const float* b_prot = (const float*)d_in[5];
    const float* c1_Ws  = (const float*)d_in[6];
    const float* c1_Wd  = (const float*)d_in[7];
    const float* c1_as  = (const float*)d_in[8];
    const float* c1_ad  = (const float*)d_in[9];
    const float* c1_b   = (const float*)d_in[10];
    const float* l1_W   = (const float*)d_in[11];
    const float* l1_b   = (const float*)d_in[12];
    const float* ln_g   = (const float*)d_in[13];
    const float* ln_b   = (const float*)d_in[14];
    const float* c2_Ws  = (const float*)d_in[15];
    const float* c2_Wd  = (const float*)d_in[16];
    const float* c2_as  = (const float*)d_in[17];
    const float* c2_ad  = (const float*)d_in[18];
    const float* c2_b   = (const float*)d_in[19];
    const float* l2_W   = (const float*)d_in[20];
    const float* l2_b   = (const float*)d_in[21];
    const float* agg_W  = (const float*)d_in[22];
    const float* agg_b  = (const float*)d_in[23];
    const float* dr_W   = (const float*)d_in[24];
    const float* dr_b   = (const float*)d_in[25];
    const float* dp_W   = (const float*)d_in[26];
    const float* dp_b   = (const float*)d_in[27];
    const float* rr_W   = (const float*)d_in[28];
    const float* rr_b   = (const float*)d_in[29];
    const float* rp_W   = (const float*)d_in[30];
    const float* rp_b   = (const float*)d_in[31];

    const int N = in_sizes[0] / 2100;   // 10000
    const int E = in_sizes[1] / 2;      // 160000
    const int Mp = ((N + 127) & ~127) + 128;

    char* wsp = (char*)d_ws;
    size_t off = 0;
    auto alloc = [&](size_t bytes) -> void* {
        void* p = wsp + off;
        off += (bytes + 255) & ~(size_t)255;
        return p;
    };
    int*      flags   = (int*)   alloc(16);
    int*      src32   = (int*)   alloc((size_t)E * 4);
    int*      dst32   = (int*)   alloc((size_t)E * 4);
    int*      cnt     = (int*)   alloc((size_t)N * 4);
    int*      cursor  = (int*)   alloc((size_t)N * 4);
    int*      row_ptr = (int*)   alloc((size_t)(N + 1) * 4);
    int*      col_src = (int*)   alloc((size_t)E * 4);
    float*    hB      = (float*) alloc((size_t)N * 512 * 4);
    float*    a_s     = (float*) alloc((size_t)N * 4 * 4);
    float*    a_d     = (float*) alloc((size_t)N * 4 * 4);
    float*    Vs      = (float*) alloc(512 * 4 * 4);
    float*    Vd      = (float*) alloc(512 * 4 * 4);
    float*    bsum1   = (float*) alloc(512 * 4);
    float*    bsum2   = (float*) alloc(512 * 4);
    float*    ddb     = (float*) alloc(256 * 4);
    // bf16 activation buffers (row-padded to Mp)
    bf16*     xbf     = (bf16*)  alloc((size_t)Mp * 2128 * 2);
    bf16*     xin_bf  = (bf16*)  alloc((size_t)Mp * 256 * 2);
    bf16*     hA_bf   = (bf16*)  alloc((size_t)Mp * 512 * 2);
    bf16*     hB_bf   = (bf16*)  alloc((size_t)Mp * 512 * 2);
    bf16*     xs      = (bf16*)  alloc((size_t)Mp * 512 * 2);
    bf16*     emb_bf  = (bf16*)  alloc((size_t)Mp * 128 * 2);
    bf16*     trp     = (bf16*)  alloc((size_t)Mp * 256 * 2);
    // bf16 transposed weights
    bf16*     wrna_t  = (bf16*)  alloc((size_t)128 * 2016 * 2);
    bf16*     wprot_t = (bf16*)  alloc((size_t)128 * 128 * 2);
    bf16*     cb1     = (bf16*)  alloc((size_t)1024 * 256 * 2);   // [c1t ; l1t]
    bf16*     cb2     = (bf16*)  alloc((size_t)1024 * 512 * 2);   // [c2t ; l2t]
    bf16*     aggt    = (bf16*)  alloc((size_t)128 * 512 * 2);
    bf16*     ddt     = (bf16*)  alloc((size_t)256 * 128 * 2);    // [drt ; dpt]
    bf16*     rrt     = (bf16*)  alloc((size_t)2048 * 128 * 2);
    bf16*     rpt     = (bf16*)  alloc((size_t)128 * 128 * 2);

    const dim3 blk64(64, 1, 1);
    const dim3 blk256(256, 1, 1);
    const dim3 gE((E + 255) / 256);
    const dim3 gN((N + 255) / 256);
    const int GY128 = (N + 127) / 128;   // 79
    const int GY64  = (N + 63) / 64;     // 157
    const int GY32  = (N + 31) / 32;     // 313
    const int NWG_DUAL = GY128 * 8;      // 632 (128-row strips x 8 col-blocks of 128)

    float* out0 = (float*)d_out;
    float* out1 = out0 + (size_t)N * 2000;
    float* out2 = out1 + (size_t)N * 100;

    // ---- edges -> CSR by dst ----
    detect_kernel<<<dim3(1), blk256, 0, stream>>>(ei, E, flags);
    conv_edges_kernel<<<gE, blk256, 0, stream>>>(ei, src32, dst32, E, N, flags);
    zero2_kernel<<<gN, blk256, 0, stream>>>(cnt, cursor, N);
    hist_kernel<<<gE, blk256, 0, stream>>>(dst32, cnt, E);
    scan_kernel<<<dim3(1), dim3(1024, 1, 1), 0, stream>>>(cnt, row_ptr, N);
    fill_csr_kernel<<<gE, blk256, 0, stream>>>(src32, dst32, row_ptr, cursor, col_src, E);

    // ---- weight converts (LDS-tiled transpose, one dispatch) ----
    {
        TTab tab{};
        int nt = 0, i = 0;
        auto add = [&](const float* s, bf16* d, int K, int Nn, int Kp, int Np) {
            tab.e[i] = {s, d, K, Nn, Kp, Np, nt};
            nt += (Kp >> 5) * (Np >> 5);
            ++i;
        };
        add(W_rna,  wrna_t,          2000, 128, 2016, 128);
        add(W_prot, wprot_t,          100, 128,  128, 128);
        add(c1_Ws,  cb1,              256, 512,  256, 512);
        add(l1_W,   cb1 + 512 * 256,  256, 512,  256, 512);
        add(c2_Ws,  cb2,              512, 512,  512, 512);
        add(l2_W,   cb2 + 512 * 512,  512, 512,  512, 512);
        add(agg_W,  aggt,             512, 128,  512, 128);
        add(dr_W,   ddt,              128, 128,  128, 128);
        add(dp_W,   ddt + 128 * 128,  128, 128,  128, 128);
        add(rr_W,   rrt,              128, 2000, 128, 2048);
        add(rp_W,   rpt,              128, 100,  128, 128);
        tab.n = i;
        wconv_t_kernel<<<dim3(nt), blk256, 0, stream>>>(tab);
    }
    bias_fuse_kernel<<<dim3(5), blk256, 0, stream>>>(l1_b, c1_b, bsum1,
                                                     l2_b, c2_b, bsum2,
                                                     dr_b, dp_b, ddb);
    make_v2_kernel<<<dim3((2 * 256 * 4 + 255) / 256), blk256, 0, stream>>>(
        c1_Ws, c1_as, Vs, c1_Wd, c1_ad, Vd, 256);

    // ---- x -> bf16 once (streaming, vectorized), then bf16-A embed GEMMs ----
    conv_x_kernel<<<dim3(N), blk256, 0, stream>>>(x, xbf);
    mfma_gemm_kernel<2, false, bf16><<<dim3(2, GY64), blk256, 0, stream>>>(
        xbf, 2128, wrna_t, 2016, b_rna, nullptr, 0, xin_bf, 256, N, 128, 2016);
    mfma_gemm_kernel<1, false, bf16><<<dim3(2, GY32), blk256, 0, stream>>>(
        xbf + 2000, 2128, wprot_t, 128, b_prot, nullptr, 0, xin_bf + 128, 256, N, 128, 128);
    logits_bf16_kernel<<<dim3(N), blk64, 0, stream>>>(xin_bf, Vs, Vd, a_s, a_d);

    // ---- block 1 ----
    mfma_gemm_dual_kernel<<<dim3(NWG_DUAL), blk256, 0, stream>>>(
        xin_bf, 256, cb1, 256, bsum1, xs, hB, N, 256, NWG_DUAL);
    gat_gather_kernel<<<dim3(N), blk64, 0, stream>>>(row_ptr, col_src, a_s, a_d, xs, hB, nullptr);

    // ---- block 2 prep ----
    make_v2_kernel<<<dim3((2 * 512 * 4 + 255) / 256), blk256, 0, stream>>>(
        c2_Ws, c2_as, Vs, c2_Wd, c2_ad, Vd, 512);
    ln_relu_logits_kernel<<<dim3(N), blk64, 0, stream>>>(
        hB, ln_g, ln_b, Vs, Vd, hA_bf, a_s, a_d);

    // ---- block 2 ----
    mfma_gemm_dual_kernel<<<dim3(NWG_DUAL), blk256, 0, stream>>>(
        hA_bf, 512, cb2, 512, bsum2, xs, hB, N, 512, NWG_DUAL);
    gat_gather_kernel<<<dim3(N), blk64, 0, stream>>>(row_ptr, col_src, a_s, a_d, xs, hB, hB_bf);

    // ---- head (all MFMA) ----
    mfma_gemm_kernel<2, true, bf16><<<dim3(2, GY64), blk256, 0, stream>>>(
        hB_bf, 512, aggt, 512, agg_b, out2, 128, emb_bf, 128, N, 128, 512);
    mfma_gemm_kernel<2, false, bf16><<<dim3(4, GY64), blk256, 0, stream>>>(
        emb_bf, 128, ddt, 128, ddb, nullptr, 0, trp, 256, N, 256, 128);
    mfma_gemm_kernel<4, false, bf16><<<dim3(32, GY128), blk256, 0, stream>>>(
        trp, 256, rrt, 128, rr_b, out0, 2000, nullptr, 0, N, 2000, 128);
    mfma_gemm_kernel<2, false, bf16><<<dim3(2, GY64), blk256, 0, stream>>>(
        trp + 128, 256, rpt, 128, rp_b, out1, 100, nullptr, 0, N, 100, 128);
}

// Round 15
// 582.852 us; speedup vs baseline: 1.0383x; 1.0101x over previous
//
#include <hip/hip_runtime.h>
#include <hip/hip_bf16.h>
#include <stdint.h>
#include <stddef.h>

using bf16  = __hip_bfloat16;
using bf162 = __hip_bfloat162;

typedef __bf16 bvec8 __attribute__((ext_vector_type(8)));
typedef float  fvec4 __attribute__((ext_vector_type(4)));

// ---------- helpers ----------
struct __align__(16) bf16x8 { bf162 a, b, c, d; };

__device__ __forceinline__ void bf8_to_f(const bf16* p, float* o) {
    bf16x8 v = *reinterpret_cast<const bf16x8*>(p);
    o[0] = __bfloat162float(v.a.x); o[1] = __bfloat162float(v.a.y);
    o[2] = __bfloat162float(v.b.x); o[3] = __bfloat162float(v.b.y);
    o[4] = __bfloat162float(v.c.x); o[5] = __bfloat162float(v.c.y);
    o[6] = __bfloat162float(v.d.x); o[7] = __bfloat162float(v.d.y);
}

__device__ __forceinline__ float wred_sum(float v) {
    #pragma unroll
    for (int o = 32; o > 0; o >>= 1) v += __shfl_xor(v, o);
    return v;
}

__device__ __forceinline__ float wred_max(float v) {
    #pragma unroll
    for (int o = 32; o > 0; o >>= 1) v = fmaxf(v, __shfl_xor(v, o));
    return v;
}

__device__ __forceinline__ float lrelu(float x) { return (x > 0.f) ? x : 0.2f * x; }

__device__ __forceinline__ fvec4 mfma16(bvec8 a, bvec8 b, fvec4 c) {
    return __builtin_amdgcn_mfma_f32_16x16x32_bf16(a, b, c, 0, 0, 0);
}

__device__ __forceinline__ bvec8 ldA(const bf16* p) {
    return *reinterpret_cast<const bvec8*>(p);
}
__device__ __forceinline__ bvec8 ldA(const float* p) {
    float4 f0 = *reinterpret_cast<const float4*>(p);
    float4 f1 = *reinterpret_cast<const float4*>(p + 4);
    union { bvec8 v; bf16 h[8]; } u;
    u.h[0] = __float2bfloat16(f0.x); u.h[1] = __float2bfloat16(f0.y);
    u.h[2] = __float2bfloat16(f0.z); u.h[3] = __float2bfloat16(f0.w);
    u.h[4] = __float2bfloat16(f1.x); u.h[5] = __float2bfloat16(f1.y);
    u.h[6] = __float2bfloat16(f1.z); u.h[7] = __float2bfloat16(f1.w);
    return u.v;
}

// ---------- edge dtype detection ----------
__global__ void detect_kernel(const int* __restrict__ ei, int E, int* __restrict__ flags) {
    __shared__ int zc;
    if (threadIdx.x == 0) zc = 0;
    __syncthreads();
    int nodd = E / 2; if (nodd > 1024) nodd = 1024;
    for (int i = threadIdx.x; i < nodd; i += blockDim.x)
        if (ei[2 * i + 1] == 0) atomicAdd(&zc, 1);
    __syncthreads();
    if (threadIdx.x == 0) flags[0] = (zc > nodd / 2) ? 1 : 0;
}

__global__ void conv_edges_kernel(const int* __restrict__ ei, int* __restrict__ src32,
                                  int* __restrict__ dst32, int E, int N,
                                  const int* __restrict__ flags) {
    const int e = blockIdx.x * blockDim.x + threadIdx.x;
    if (e >= E) return;
    int s, d;
    if (flags[0]) { s = ei[2 * e]; d = ei[2 * (E + e)]; }
    else          { s = ei[e];     d = ei[E + e]; }
    src32[e] = (s < 0) ? 0 : ((s >= N) ? N - 1 : s);
    dst32[e] = (d < 0) ? 0 : ((d >= N) ? N - 1 : d);
}

// ---------- CSR build ----------
__global__ void zero2_kernel(int* __restrict__ p1, int* __restrict__ p2, int n) {
    int i = blockIdx.x * blockDim.x + threadIdx.x;
    if (i < n) { p1[i] = 0; p2[i] = 0; }
}

__global__ void hist_kernel(const int* __restrict__ dst32, int* __restrict__ cnt, int E) {
    int e = blockIdx.x * blockDim.x + threadIdx.x;
    if (e < E) atomicAdd(&cnt[dst32[e]], 1);
}

// 16-wave shfl-based exclusive scan: cnt[0..N) -> row_ptr[0..N]
__global__ __launch_bounds__(1024) void scan_kernel(const int* __restrict__ cnt,
                                                    int* __restrict__ row_ptr, int N) {
    __shared__ int wsum[16];
    __shared__ int carry;
    const int tid = threadIdx.x, lane = tid & 63, wid = tid >> 6;
    if (tid == 0) { carry = 0; row_ptr[0] = 0; }
    __syncthreads();
    for (int base = 0; base < N; base += 1024) {
        int i = base + tid;
        int v = (i < N) ? cnt[i] : 0;
        int s = v;
        #pragma unroll
        for (int o = 1; o < 64; o <<= 1) {
            int t = __shfl_up(s, o);
            if (lane >= o) s += t;
        }
        if (lane == 63) wsum[wid] = s;
        __syncthreads();
        if (wid == 0 && lane < 16) {
            int ws = wsum[lane];
            #pragma unroll
            for (int o = 1; o < 16; o <<= 1) {
                int t = __shfl_up(ws, o);
                if (lane >= o) ws += t;
            }
            wsum[lane] = ws;
        }
        __syncthreads();
        int add = carry + (wid > 0 ? wsum[wid - 1] : 0);
        if (i < N) row_ptr[i + 1] = s + add;
        __syncthreads();
        if (tid == 0) carry += wsum[15];
        __syncthreads();
    }
}

__global__ void fill_csr_kernel(const int* __restrict__ src32, const int* __restrict__ dst32,
                                const int* __restrict__ row_ptr, int* __restrict__ cursor,
                                int* __restrict__ col_src, int E) {
    int e = blockIdx.x * blockDim.x + threadIdx.x;
    if (e >= E) return;
    int d = dst32[e];
    int pos = atomicAdd(&cursor[d], 1);
    col_src[row_ptr[d] + pos] = src32[e];
}

// ---------- all weight converts, LDS-tiled transpose (coalesced both sides) ----------
struct TEnt { const float* src; bf16* dst; int K, N, Kp, Np, tstart; };
struct TTab { TEnt e[12]; int n; };

__global__ __launch_bounds__(256) void wconv_t_kernel(TTab tab) {
    __shared__ float tile[32][33];
    const int b = blockIdx.x;
    int wi = 0;
    #pragma unroll 1
    for (int i = 1; i < tab.n; ++i) if (b >= tab.e[i].tstart) wi = i;
    const TEnt w = tab.e[wi];
    const int tidx = b - w.tstart;
    const int ntk = w.Kp >> 5;
    const int tn = tidx / ntk, tk = tidx - tn * ntk;
    const int k0 = tk * 32, n0 = tn * 32;
    const int tx = threadIdx.x & 31, ty = threadIdx.x >> 5;   // 32 x 8
    #pragma unroll
    for (int j = 0; j < 4; ++j) {
        int k = k0 + ty * 4 + j;
        int n = n0 + tx;
        tile[ty * 4 + j][tx] = (k < w.K && n < w.N) ? w.src[(size_t)k * w.N + n] : 0.f;
    }
    __syncthreads();
    #pragma unroll
    for (int j = 0; j < 4; ++j) {
        int n = n0 + ty * 4 + j;
        int k = k0 + tx;
        w.dst[(size_t)n * w.Kp + k] = __float2bfloat16(tile[tx][ty * 4 + j]);
    }
}

// ---------- x -> bf16, row stride 2128, fully vectorized ----------
__global__ __launch_bounds__(256) void conv_x_kernel(const float* __restrict__ x,
                                                     bf16* __restrict__ xbf) {
    const int r = blockIdx.x;
    const float* xr = x + (size_t)r * 2100;
    bf16* orow = xbf + (size_t)r * 2128;
    #pragma unroll
    for (int pass = 0; pass < 2; ++pass) {
        int c0 = pass * 2048 + threadIdx.x * 8;
        if (c0 >= 2128) continue;
        union { uint4 u; bf16 h[8]; } ob;
        if (c0 + 8 <= 2100) {
            float4 f0 = *reinterpret_cast<const float4*>(xr + c0);
            float4 f1 = *reinterpret_cast<const float4*>(xr + c0 + 4);
            ob.h[0] = __float2bfloat16(f0.x); ob.h[1] = __float2bfloat16(f0.y);
            ob.h[2] = __float2bfloat16(f0.z); ob.h[3] = __float2bfloat16(f0.w);
            ob.h[4] = __float2bfloat16(f1.x); ob.h[5] = __float2bfloat16(f1.y);
            ob.h[6] = __float2bfloat16(f1.z); ob.h[7] = __float2bfloat16(f1.w);
        } else {
            #pragma unroll
            for (int j = 0; j < 8; ++j) {
                int c = c0 + j;
                ob.h[j] = __float2bfloat16((c < 2100) ? xr[c] : 0.f);
            }
        }
        *reinterpret_cast<uint4*>(orow + c0) = ob.u;
    }
}

// ---------- fused bias prep ----------
__global__ void bias_fuse_kernel(const float* l1_b, const float* c1_b, float* bsum1,
                                 const float* l2_b, const float* c2_b, float* bsum2,
                                 const float* dr_b, const float* dp_b, float* ddb) {
    int i = blockIdx.x * blockDim.x + threadIdx.x;
    if (i < 512)       bsum1[i] = l1_b[i] + c1_b[i];
    else if (i < 1024) bsum2[i - 512] = l2_b[i - 512] + c2_b[i - 512];
    else if (i < 1152) ddb[i - 1024] = dr_b[i - 1024];
    else if (i < 1280) ddb[i - 1024] = dp_b[i - 1152];
}

// ---------- block-1 logits from xin_bf: one wave per node, K=256 ----------
__global__ __launch_bounds__(64) void logits_bf16_kernel(
    const bf16* __restrict__ X,
    const float* __restrict__ Vs, const float* __restrict__ Vd,
    float* __restrict__ a_s, float* __restrict__ a_d)
{
    const int n = blockIdx.x, lane = threadIdx.x;
    const int c0 = lane * 4;
    union { uint2 u; bf16 h[4]; } ub;
    ub.u = *reinterpret_cast<const uint2*>(X + (size_t)n * 256 + c0);
    const float vv[4] = {__bfloat162float(ub.h[0]), __bfloat162float(ub.h[1]),
                         __bfloat162float(ub.h[2]), __bfloat162float(ub.h[3])};
    float ss0=0,ss1=0,ss2=0,ss3=0, dd0=0,dd1=0,dd2=0,dd3=0;
    #pragma unroll
    for (int j = 0; j < 4; ++j) {
        float4 vs = *reinterpret_cast<const float4*>(Vs + (size_t)(c0 + j) * 4);
        float4 vd = *reinterpret_cast<const float4*>(Vd + (size_t)(c0 + j) * 4);
        ss0 = fmaf(vv[j], vs.x, ss0); ss1 = fmaf(vv[j], vs.y, ss1);
        ss2 = fmaf(vv[j], vs.z, ss2); ss3 = fmaf(vv[j], vs.w, ss3);
        dd0 = fmaf(vv[j], vd.x, dd0); dd1 = fmaf(vv[j], vd.y, dd1);
        dd2 = fmaf(vv[j], vd.z, dd2); dd3 = fmaf(vv[j], vd.w, dd3);
    }
    ss0 = wred_sum(ss0); ss1 = wred_sum(ss1); ss2 = wred_sum(ss2); ss3 = wred_sum(ss3);
    dd0 = wred_sum(dd0); dd1 = wred_sum(dd1); dd2 = wred_sum(dd2); dd3 = wred_sum(dd3);
    if (lane == 0) {
        a_s[n*4+0]=ss0; a_s[n*4+1]=ss1; a_s[n*4+2]=ss2; a_s[n*4+3]=ss3;
        a_d[n*4+0]=dd0; a_d[n*4+1]=dd1; a_d[n*4+2]=dd2; a_d[n*4+3]=dd3;
    }
}

// ---------- MFMA GEMM: C[M,Nn] = A[M,K] @ Bt[Nn,K]^T (+bias, relu) ----------
template <int FM, bool RELU, typename AT>
__global__ __launch_bounds__(256) void mfma_gemm_kernel(
    const AT* __restrict__ A, int lda,
    const bf16* __restrict__ Bt, int ldb,
    const float* __restrict__ bias,
    float* __restrict__ Cf, int ldcf,
    bf16* __restrict__ Cb, int ldcb,
    int M, int Nn, int K)
{
    const int tid  = threadIdx.x;
    const int w    = tid >> 6, lane = tid & 63;
    const int wr   = w >> 1,   wc   = w & 1;
    const int m0   = blockIdx.y * (FM * 32) + wr * (FM * 16);
    const int n0   = blockIdx.x * 64 + wc * 32;
    const int lrow = lane & 15;
    const int lk8  = (lane >> 4) * 8;

    const AT* Ap[FM];
    #pragma unroll
    for (int i = 0; i < FM; ++i) {
        int r = m0 + i * 16 + lrow;
        if (r > M - 1) r = M - 1;
        Ap[i] = A + (size_t)r * lda + lk8;
    }
    const bf16* Bp = Bt + (size_t)(n0 + lrow) * ldb + lk8;
    const size_t b16 = (size_t)16 * ldb;

    fvec4 acc[FM][2];
    const fvec4 z = {0.f, 0.f, 0.f, 0.f};
    #pragma unroll
    for (int i = 0; i < FM; ++i) { acc[i][0] = z; acc[i][1] = z; }

    #pragma unroll 2
    for (int k = 0; k < K; k += 32) {
        bvec8 b0 = *reinterpret_cast<const bvec8*>(Bp + k);
        bvec8 b1 = *reinterpret_cast<const bvec8*>(Bp + k + b16);
        #pragma unroll
        for (int i = 0; i < FM; ++i) {
            bvec8 a = ldA(Ap[i] + k);
            acc[i][0] = mfma16(a, b0, acc[i][0]);
            acc[i][1] = mfma16(a, b1, acc[i][1]);
        }
    }

    const int r4 = (lane >> 4) * 4;
    #pragma unroll
    for (int fn = 0; fn < 2; ++fn) {
        const int col = n0 + fn * 16 + lrow;
        if (col >= Nn) continue;
        const float bz = bias ? bias[col] : 0.f;
        #pragma unroll
        for (int fm = 0; fm < FM; ++fm) {
            const int rbase = m0 + fm * 16 + r4;
            #pragma unroll
            for (int r = 0; r < 4; ++r) {
                const int row = rbase + r;
                if (row >= M) continue;
                float v = acc[fm][fn][r] + bz;
                if (RELU) v = fmaxf(v, 0.f);
                if (Cf) Cf[(size_t)row * ldcf + col] = v;
                if (Cb) Cb[(size_t)row * ldcb + col] = __float2bfloat16(v);
            }
        }
    }
}

// ---------- dual-output MFMA GEMM, 128x128 block, 4 waves, wave tile 64x64 ----------
// 1D grid, bijective chunked XCD swizzle.
__global__ __launch_bounds__(256) void mfma_gemm_dual_kernel(
    const bf16* __restrict__ A, int lda,
    const bf16* __restrict__ Bt, int ldb,
    const float* __restrict__ biasU,
    bf16* __restrict__ xs, float* __restrict__ hB,
    int M, int K, int nwg)
{
    const int bid = blockIdx.x;
    const int q = nwg >> 3, r = nwg & 7;
    const int xcd = bid & 7, idx = bid >> 3;
    const int sbid = (xcd < r ? xcd * (q + 1) : r * (q + 1) + (xcd - r) * q) + idx;
    const int by = sbid >> 3, bx = sbid & 7;

    const int tid  = threadIdx.x;
    const int w    = tid >> 6, lane = tid & 63;
    const int wr   = w >> 1,   wc   = w & 1;
    const int m0   = by * 128 + wr * 64;
    const int n0   = bx * 128 + wc * 64;
    const int lrow = lane & 15;
    const int lk8  = (lane >> 4) * 8;

    const bf16* Ap[4];
    const bf16* Bp[4];
    #pragma unroll
    for (int i = 0; i < 4; ++i) {
        int rr = m0 + i * 16 + lrow;
        if (rr > M - 1) rr = M - 1;
        Ap[i] = A + (size_t)rr * lda + lk8;
        Bp[i] = Bt + (size_t)(n0 + i * 16 + lrow) * ldb + lk8;
    }

    fvec4 acc[4][4];
    const fvec4 z = {0.f, 0.f, 0.f, 0.f};
    #pragma unroll
    for (int i = 0; i < 4; ++i)
        #pragma unroll
        for (int j = 0; j < 4; ++j) acc[i][j] = z;

    #pragma unroll 2
    for (int k = 0; k < K; k += 32) {
        bvec8 a[4], b[4];
        #pragma unroll
        for (int i = 0; i < 4; ++i) a[i] = *reinterpret_cast<const bvec8*>(Ap[i] + k);
        #pragma unroll
        for (int j = 0; j < 4; ++j) b[j] = *reinterpret_cast<const bvec8*>(Bp[j] + k);
        #pragma unroll
        for (int i = 0; i < 4; ++i)
            #pragma unroll
            for (int j = 0; j < 4; ++j)
                acc[i][j] = mfma16(a[i], b[j], acc[i][j]);
    }

    const int r4 = (lane >> 4) * 4;
    #pragma unroll
    for (int fn = 0; fn < 4; ++fn) {
        const int col = n0 + fn * 16 + lrow;
        if (col < 512) {
            #pragma unroll
            for (int fm = 0; fm < 4; ++fm) {
                const int rbase = m0 + fm * 16 + r4;
                #pragma unroll
                for (int rr = 0; rr < 4; ++rr) {
                    const int row = rbase + rr;
                    if (row >= M) continue;
                    xs[(size_t)row * 512 + col] = __float2bfloat16(acc[fm][fn][rr]);
                }
            }
        } else {
            const int c2 = col - 512;
            const float bz = biasU[c2];
            #pragma unroll
            for (int fm = 0; fm < 4; ++fm) {
                const int rbase = m0 + fm * 16 + r4;
                #pragma unroll
                for (int rr = 0; rr < 4; ++rr) {
                    const int row = rbase + rr;
                    if (row >= M) continue;
                    hB[(size_t)row * 512 + c2] = acc[fm][fn][rr] + bz;
                }
            }
        }
    }
}

// ---------- V tables for both s and d in one dispatch ----------
__global__ void make_v2_kernel(const float* __restrict__ Ws, const float* __restrict__ atts,
                               float* __restrict__ Vs,
                               const float* __restrict__ Wd, const float* __restrict__ attd,
                               float* __restrict__ Vd, int K)
{
    int t = blockIdx.x * blockDim.x + threadIdx.x;
    const int half = K * 4;
    if (t >= 2 * half) return;
    const float* W   = (t < half) ? Ws : Wd;
    const float* att = (t < half) ? atts : attd;
    float* V         = (t < half) ? Vs : Vd;
    int tt = (t < half) ? t : t - half;
    int k = tt >> 2, h = tt & 3;
    float s = 0.f;
    const float* wp = W + (size_t)k * 512 + h * 128;
    const float* ap = att + h * 128;
    #pragma unroll 4
    for (int c = 0; c < 128; ++c)
        s = fmaf(wp[c], ap[c], s);
    V[k * 4 + h] = s;
}

// ---------- fused GAT aggregation v2: online softmax + LDS edge/weight cache ----------
// One wave per dst node. Pass A: online (max,sum) per head, cache col_src in LDS.
// Pass A2: precompute normalized per-head weights into LDS. Pass B: serial
// accumulate with 1-deep (s,w) prefetch - no gathers/expf in the chain.
#define GCAP 256
__global__ __launch_bounds__(64) void gat_gather_kernel(
    const int* __restrict__ row_ptr, const int* __restrict__ col_src,
    const float* __restrict__ a_s, const float* __restrict__ a_d,
    const bf16* __restrict__ xs, float* __restrict__ hout,
    bf16* __restrict__ hout_bf)
{
    __shared__ int   ls[GCAP];
    __shared__ float lw[GCAP * 4];

    const int d = blockIdx.x, lane = threadIdx.x;
    const int beg = row_ptr[d], end = row_ptr[d + 1];
    const int deg = end - beg;
    const float4 ad = *reinterpret_cast<const float4*>(a_d + (size_t)d * 4);

    // ---- pass A: per-lane online softmax over strided edges; cache s in LDS ----
    float m0=-1e30f, m1=-1e30f, m2=-1e30f, m3=-1e30f;
    float s0=0.f, s1=0.f, s2=0.f, s3=0.f;
    for (int i = beg + lane; i < end; i += 64) {
        int s = col_src[i];
        int j = i - beg;
        if (j < GCAP) ls[j] = s;
        float4 as = *reinterpret_cast<const float4*>(a_s + (size_t)s * 4);
        float l0 = lrelu(as.x + ad.x), l1 = lrelu(as.y + ad.y);
        float l2 = lrelu(as.z + ad.z), l3 = lrelu(as.w + ad.w);
        float n0 = fmaxf(m0, l0); s0 = s0 * __expf(m0 - n0) + __expf(l0 - n0); m0 = n0;
        float n1 = fmaxf(m1, l1); s1 = s1 * __expf(m1 - n1) + __expf(l1 - n1); m1 = n1;
        float n2 = fmaxf(m2, l2); s2 = s2 * __expf(m2 - n2) + __expf(l2 - n2); m2 = n2;
        float n3 = fmaxf(m3, l3); s3 = s3 * __expf(m3 - n3) + __expf(l3 - n3); m3 = n3;
    }
    const float M0 = wred_max(m0), M1 = wred_max(m1);
    const float M2 = wred_max(m2), M3 = wred_max(m3);
    s0 = wred_sum(s0 * __expf(m0 - M0));
    s1 = wred_sum(s1 * __expf(m1 - M1));
    s2 = wred_sum(s2 * __expf(m2 - M2));
    s3 = wred_sum(s3 * __expf(m3 - M3));
    const float i0 = 1.f / (s0 + 1e-16f), i1 = 1.f / (s1 + 1e-16f);
    const float i2 = 1.f / (s2 + 1e-16f), i3 = 1.f / (s3 + 1e-16f);

    // ---- pass A2: normalized per-head weights into LDS (parallel over lanes) ----
    for (int i = beg + lane; i < end; i += 64) {
        int j = i - beg;
        if (j >= GCAP) break;
        int s = ls[j];
        float4 as = *reinterpret_cast<const float4*>(a_s + (size_t)s * 4);
        float4 wv;
        wv.x = __expf(lrelu(as.x + ad.x) - M0) * i0;
        wv.y = __expf(lrelu(as.y + ad.y) - M1) * i1;
        wv.z = __expf(lrelu(as.z + ad.z) - M2) * i2;
        wv.w = __expf(lrelu(as.w + ad.w) - M3) * i3;
        *reinterpret_cast<float4*>(lw + (size_t)j * 4) = wv;
    }

    // ---- pass B: serial accumulate with 1-deep prefetch ----
    const int h  = lane >> 4;
    const int c0 = lane * 8;
    float acc[8] = {0.f,0.f,0.f,0.f,0.f,0.f,0.f,0.f};
    const int jmax = (deg < GCAP) ? deg : GCAP;
    if (jmax > 0) {
        int   s_cur = ls[0];
        float w_cur = lw[h];
        for (int j = 0; j < jmax; ++j) {
            int   s_nxt = 0;
            float w_nxt = 0.f;
            if (j + 1 < jmax) { s_nxt = ls[j + 1]; w_nxt = lw[(size_t)(j + 1) * 4 + h]; }
            float xv[8];
            bf8_to_f(xs + (size_t)s_cur * 512 + c0, xv);
            #pragma unroll
            for (int t = 0; t < 8; ++t) acc[t] = fmaf(w_cur, xv[t], acc[t]);
            s_cur = s_nxt; w_cur = w_nxt;
        }
    }
    // tail beyond LDS cap (rare): original gather path
    if (deg > GCAP) {
        const float Mh  = (h == 0) ? M0 : ((h == 1) ? M1 : ((h == 2) ? M2 : M3));
        const float ih  = (h == 0) ? i0 : ((h == 1) ? i1 : ((h == 2) ? i2 : i3));
        const float adh = (h == 0) ? ad.x : ((h == 1) ? ad.y : ((h == 2) ? ad.z : ad.w));
        for (int i = beg + GCAP; i < end; ++i) {
            int s = col_src[i];
            float coef = __expf(lrelu(a_s[(size_t)s * 4 + h] + adh) - Mh) * ih;
            float xv[8];
            bf8_to_f(xs + (size_t)s * 512 + c0, xv);
            #pragma unroll
            for (int t = 0; t < 8; ++t) acc[t] = fmaf(coef, xv[t], acc[t]);
        }
    }

    float* hp = hout + (size_t)d * 512 + c0;
    if (hout_bf) {
        bf16* hb = hout_bf + (size_t)d * 512 + c0;
        #pragma unroll
        for (int t = 0; t < 8; ++t) {
            float fv = hp[t] + acc[t];
            hp[t] = fv;
            hb[t] = __float2bfloat16(fv);
        }
    } else {
        #pragma unroll
        for (int t = 0; t < 8; ++t) hp[t] += acc[t];
    }
}

// ---------- LN+ReLU -> hA_bf, fused with block-2 logits ----------
__global__ __launch_bounds__(64) void ln_relu_logits_kernel(
    const float* __restrict__ in, const float* __restrict__ g,
    const float* __restrict__ b,
    const float* __restrict__ Vs, const float* __restrict__ Vd,
    bf16* __restrict__ outbf, float* __restrict__ a_s, float* __restrict__ a_d)
{
    const int n = blockIdx.x, lane = threadIdx.x;
    const int c0 = lane * 8;
    const float* ip = in + (size_t)n * 512 + c0;
    float v[8];
    float4 p0 = *reinterpret_cast<const float4*>(ip);
    float4 p1 = *reinterpret_cast<const float4*>(ip + 4);
    v[0]=p0.x; v[1]=p0.y; v[2]=p0.z; v[3]=p0.w; v[4]=p1.x; v[5]=p1.y; v[6]=p1.z; v[7]=p1.w;
    float s = 0.f;
    #pragma unroll
    for (int t = 0; t < 8; ++t) s += v[t];
    s = wred_sum(s);
    const float mu = s * (1.0f / 512.0f);
    float q = 0.f;
    #pragma unroll
    for (int t = 0; t < 8; ++t) { float dlt = v[t] - mu; q = fmaf(dlt, dlt, q); }
    q = wred_sum(q);
    const float sc = rsqrtf(q * (1.0f / 512.0f) + 1e-5f);
    float4 g0 = *reinterpret_cast<const float4*>(g + c0);
    float4 g1 = *reinterpret_cast<const float4*>(g + c0 + 4);
    float4 b0 = *reinterpret_cast<const float4*>(b + c0);
    float4 b1 = *reinterpret_cast<const float4*>(b + c0 + 4);
    const float gv[8] = {g0.x,g0.y,g0.z,g0.w,g1.x,g1.y,g1.z,g1.w};
    const float bv[8] = {b0.x,b0.y,b0.z,b0.w,b1.x,b1.y,b1.z,b1.w};
    float r[8];
    bf16* ob = outbf + (size_t)n * 512 + c0;
    #pragma unroll
    for (int t = 0; t < 8; ++t) {
        r[t] = fmaxf(0.f, fmaf((v[t] - mu) * sc, gv[t], bv[t]));
        ob[t] = __float2bfloat16(r[t]);
    }
    float ss0=0,ss1=0,ss2=0,ss3=0, dd0=0,dd1=0,dd2=0,dd3=0;
    #pragma unroll
    for (int t = 0; t < 8; ++t) {
        float4 vs = *reinterpret_cast<const float4*>(Vs + (size_t)(c0 + t) * 4);
        float4 vd = *reinterpret_cast<const float4*>(Vd + (size_t)(c0 + t) * 4);
        ss0 = fmaf(r[t], vs.x, ss0); ss1 = fmaf(r[t], vs.y, ss1);
        ss2 = fmaf(r[t], vs.z, ss2); ss3 = fmaf(r[t], vs.w, ss3);
        dd0 = fmaf(r[t], vd.x, dd0); dd1 = fmaf(r[t], vd.y, dd1);
        dd2 = fmaf(r[t], vd.z, dd2); dd3 = fmaf(r[t], vd.w, dd3);
    }
    ss0 = wred_sum(ss0); ss1 = wred_sum(ss1); ss2 = wred_sum(ss2); ss3 = wred_sum(ss3);
    dd0 = wred_sum(dd0); dd1 = wred_sum(dd1); dd2 = wred_sum(dd2); dd3 = wred_sum(dd3);
    if (lane == 0) {
        a_s[n*4+0]=ss0; a_s[n*4+1]=ss1; a_s[n*4+2]=ss2; a_s[n*4+3]=ss3;
        a_d[n*4+0]=dd0; a_d[n*4+1]=dd1; a_d[n*4+2]=dd2; a_d[n*4+3]=dd3;
    }
}

// ---------- launcher ----------
extern "C" void kernel_launch(void* const* d_in, const int* in_sizes, int n_in,
                              void* d_out, int out_size, void* d_ws, size_t ws_size,
                              hipStream_t stream)
{
    (void)n_in; (void)out_size; (void)ws_size;
    const float* x   = (const float*)d_in[0];
    const int*   ei  = (const int*)d_in[1];

    const float* W_rna  = (const float*)d_in[2];
    const float* b_rna  = (const float*)d_in[3];
    const float* W_prot = (const float*)d_in[4];
    const float* b_prot = (const float*)d_in[5];
    const float* c1_Ws  = (const float*)d_in[6];
    const float* c1_Wd  = (const float*)d_in[7];
    const float* c1_as  = (const float*)d_in[8];
    const float* c1_ad  = (const float*)d_in[9];
    const float* c1_b   = (const float*)d_in[10];
    const float* l1_W   = (const float*)d_in[11];
    const float* l1_b   = (const float*)d_in[12];
    const float* ln_g   = (const float*)d_in[13];
    const float* ln_b   = (const float*)d_in[14];
    const float* c2_Ws  = (const float*)d_in[15];
    const float* c2_Wd  = (const float*)d_in[16];
    const float* c2_as  = (const float*)d_in[17];
    const float* c2_ad  = (const float*)d_in[18];
    const float* c2_b   = (const float*)d_in[19];
    const float* l2_W   = (const float*)d_in[20];
    const float* l2_b   = (const float*)d_in[21];
    const float* agg_W  = (const float*)d_in[22];
    const float* agg_b  = (const float*)d_in[23];
    const float* dr_W   = (const float*)d_in[24];
    const float* dr_b   = (const float*)d_in[25];
    const float* dp_W   = (const float*)d_in[26];
    const float* dp_b   = (const float*)d_in[27];
    const float* rr_W   = (const float*)d_in[28];
    const float* rr_b   = (const float*)d_in[29];
    const float* rp_W   = (const float*)d_in[30];
    const float* rp_b   = (const float*)d_in[31];

    const int N = in_sizes[0] / 2100;   // 10000
    const int E = in_sizes[1] / 2;      // 160000
    const int Mp = ((N + 127) & ~127) + 128;

    char* wsp = (char*)d_ws;
    size_t off = 0;
    auto alloc = [&](size_t bytes) -> void* {
        void* p = wsp + off;
        off += (bytes + 255) & ~(size_t)255;
        return p;
    };
    int*      flags   = (int*)   alloc(16);
    int*      src32   = (int*)   alloc((size_t)E * 4);
    int*      dst32   = (int*)   alloc((size_t)E * 4);
    int*      cnt     = (int*)   alloc((size_t)N * 4);
    int*      cursor  = (int*)   alloc((size_t)N * 4);
    int*      row_ptr = (int*)   alloc((size_t)(N + 1) * 4);
    int*      col_src = (int*)   alloc((size_t)E * 4);
    float*    hB      = (float*) alloc((size_t)N * 512 * 4);
    float*    a_s     = (float*) alloc((size_t)N * 4 * 4);
    float*    a_d     = (float*) alloc((size_t)N * 4 * 4);
    float*    Vs      = (float*) alloc(512 * 4 * 4);
    float*    Vd      = (float*) alloc(512 * 4 * 4);
    float*    bsum1   = (float*) alloc(512 * 4);
    float*    bsum2   = (float*) alloc(512 * 4);
    float*    ddb     = (float*) alloc(256 * 4);
    // bf16 activation buffers (row-padded to Mp)
    bf16*     xbf     = (bf16*)  alloc((size_t)Mp * 2128 * 2);
    bf16*     xin_bf  = (bf16*)  alloc((size_t)Mp * 256 * 2);
    bf16*     hA_bf   = (bf16*)  alloc((size_t)Mp * 512 * 2);
    bf16*     hB_bf   = (bf16*)  alloc((size_t)Mp * 512 * 2);
    bf16*     xs      = (bf16*)  alloc((size_t)Mp * 512 * 2);
    bf16*     emb_bf  = (bf16*)  alloc((size_t)Mp * 128 * 2);
    bf16*     trp     = (bf16*)  alloc((size_t)Mp * 256 * 2);
    // bf16 transposed weights
    bf16*     wrna_t  = (bf16*)  alloc((size_t)128 * 2016 * 2);
    bf16*     wprot_t = (bf16*)  alloc((size_t)128 * 128 * 2);
    bf16*     cb1     = (bf16*)  alloc((size_t)1024 * 256 * 2);   // [c1t ; l1t]
    bf16*     cb2     = (bf16*)  alloc((size_t)1024 * 512 * 2);   // [c2t ; l2t]
    bf16*     aggt    = (bf16*)  alloc((size_t)128 * 512 * 2);
    bf16*     ddt     = (bf16*)  alloc((size_t)256 * 128 * 2);    // [drt ; dpt]
    bf16*     rrt     = (bf16*)  alloc((size_t)2048 * 128 * 2);
    bf16*     rpt     = (bf16*)  alloc((size_t)128 * 128 * 2);

    const dim3 blk64(64, 1, 1);
    const dim3 blk256(256, 1, 1);
    const dim3 gE((E + 255) / 256);
    const dim3 gN((N + 255) / 256);
    const int GY128 = (N + 127) / 128;   // 79
    const int GY64  = (N + 63) / 64;     // 157
    const int GY32  = (N + 31) / 32;     // 313
    const int NWG_DUAL = GY128 * 8;      // 632

    float* out0 = (float*)d_out;
    float* out1 = out0 + (size_t)N * 2000;
    float* out2 = out1 + (size_t)N * 100;

    // ---- edges -> CSR by dst ----
    detect_kernel<<<dim3(1), blk256, 0, stream>>>(ei, E, flags);
    conv_edges_kernel<<<gE, blk256, 0, stream>>>(ei, src32, dst32, E, N, flags);
    zero2_kernel<<<gN, blk256, 0, stream>>>(cnt, cursor, N);
    hist_kernel<<<gE, blk256, 0, stream>>>(dst32, cnt, E);
    scan_kernel<<<dim3(1), dim3(1024, 1, 1), 0, stream>>>(cnt, row_ptr, N);
    fill_csr_kernel<<<gE, blk256, 0, stream>>>(src32, dst32, row_ptr, cursor, col_src, E);

    // ---- weight converts (LDS-tiled transpose, one dispatch) ----
    {
        TTab tab{};
        int nt = 0, i = 0;
        auto add = [&](const float* s, bf16* d, int K, int Nn, int Kp, int Np) {
            tab.e[i] = {s, d, K, Nn, Kp, Np, nt};
            nt += (Kp >> 5) * (Np >> 5);
            ++i;
        };
        add(W_rna,  wrna_t,          2000, 128, 2016, 128);
        add(W_prot, wprot_t,          100, 128,  128, 128);
        add(c1_Ws,  cb1,              256, 512,  256, 512);
        add(l1_W,   cb1 + 512 * 256,  256, 512,  256, 512);
        add(c2_Ws,  cb2,              512, 512,  512, 512);
        add(l2_W,   cb2 + 512 * 512,  512, 512,  512, 512);
        add(agg_W,  aggt,             512, 128,  512, 128);
        add(dr_W,   ddt,              128, 128,  128, 128);
        add(dp_W,   ddt + 128 * 128,  128, 128,  128, 128);
        add(rr_W,   rrt,              128, 2000, 128, 2048);
        add(rp_W,   rpt,              128, 100,  128, 128);
        tab.n = i;
        wconv_t_kernel<<<dim3(nt), blk256, 0, stream>>>(tab);
    }
    bias_fuse_kernel<<<dim3(5), blk256, 0, stream>>>(l1_b, c1_b, bsum1,
                                                     l2_b, c2_b, bsum2,
                                                     dr_b, dp_b, ddb);
    make_v2_kernel<<<dim3((2 * 256 * 4 + 255) / 256), blk256, 0, stream>>>(
        c1_Ws, c1_as, Vs, c1_Wd, c1_ad, Vd, 256);

    // ---- x -> bf16 once (streaming, vectorized), then bf16-A embed GEMMs ----
    conv_x_kernel<<<dim3(N), blk256, 0, stream>>>(x, xbf);
    mfma_gemm_kernel<2, false, bf16><<<dim3(2, GY64), blk256, 0, stream>>>(
        xbf, 2128, wrna_t, 2016, b_rna, nullptr, 0, xin_bf, 256, N, 128, 2016);
    mfma_gemm_kernel<1, false, bf16><<<dim3(2, GY32), blk256, 0, stream>>>(
        xbf + 2000, 2128, wprot_t, 128, b_prot, nullptr, 0, xin_bf + 128, 256, N, 128, 128);
    logits_bf16_kernel<<<dim3(N), blk64, 0, stream>>>(xin_bf, Vs, Vd, a_s, a_d);

    // ---- block 1 ----
    mfma_gemm_dual_kernel<<<dim3(NWG_DUAL), blk256, 0, stream>>>(
        xin_bf, 256, cb1, 256, bsum1, xs, hB, N, 256, NWG_DUAL);
    gat_gather_kernel<<<dim3(N), blk64, 0, stream>>>(row_ptr, col_src, a_s, a_d, xs, hB, nullptr);

    // ---- block 2 prep ----
    make_v2_kernel<<<dim3((2 * 512 * 4 + 255) / 256), blk256, 0, stream>>>(
        c2_Ws, c2_as, Vs, c2_Wd, c2_ad, Vd, 512);
    ln_relu_logits_kernel<<<dim3(N), blk64, 0, stream>>>(
        hB, ln_g, ln_b, Vs, Vd, hA_bf, a_s, a_d);

    // ---- block 2 ----
    mfma_gemm_dual_kernel<<<dim3(NWG_DUAL), blk256, 0, stream>>>(
        hA_bf, 512, cb2, 512, bsum2, xs, hB, N, 512, NWG_DUAL);
    gat_gather_kernel<<<dim3(N), blk64, 0, stream>>>(row_ptr, col_src, a_s, a_d, xs, hB, hB_bf);

    // ---- head (all MFMA) ----
    mfma_gemm_kernel<2, true, bf16><<<dim3(2, GY64), blk256, 0, stream>>>(
        hB_bf, 512, aggt, 512, agg_b, out2, 128, emb_bf, 128, N, 128, 512);
    mfma_gemm_kernel<2, false, bf16><<<dim3(4, GY64), blk256, 0, stream>>>(
        emb_bf, 128, ddt, 128, ddb, nullptr, 0, trp, 256, N, 256, 128);
    mfma_gemm_kernel<4, false, bf16><<<dim3(32, GY128), blk256, 0, stream>>>(
        trp, 256, rrt, 128, rr_b, out0, 2000, nullptr, 0, N, 2000, 128);
    mfma_gemm_kernel<2, false, bf16><<<dim3(2, GY64), blk256, 0, stream>>>(
        trp + 128, 256, rpt, 128, rp_b, out1, 100, nullptr, 0, N, 100, 128);
}